// Round 12
// baseline (108.173 us; speedup 1.0000x reference)
//
#include <hip/hip_runtime.h>

typedef __attribute__((ext_vector_type(8))) short bf16x8;
typedef __attribute__((ext_vector_type(4))) float f32x4;
typedef __attribute__((ext_vector_type(16))) float f32x16;
typedef __attribute__((ext_vector_type(4))) float fl4;
typedef __attribute__((ext_vector_type(8))) unsigned short u16x8;
typedef __attribute__((ext_vector_type(4))) unsigned short u16x4;
typedef __attribute__((ext_vector_type(2))) int i32x2;
typedef __attribute__((ext_vector_type(4))) int i32x4;

#define MFMA16(A,B,C) __builtin_amdgcn_mfma_f32_16x16x32_bf16((A),(B),(C),0,0,0)
#define MFMA32(A,B,C) __builtin_amdgcn_mfma_f32_32x32x16_bf16((A),(B),(C),0,0,0)

#if __has_builtin(__builtin_amdgcn_exp2f)
#define EXP2R(x) __builtin_amdgcn_exp2f(x)
#else
#define EXP2R(x) exp2f(x)
#endif

__device__ __forceinline__ unsigned short f2bf_bits(float x) {
  union { float f; unsigned u; } v; v.f = x;
  unsigned r = v.u + 0x7fffu + ((v.u >> 16) & 1u);  // RTNE
  return (unsigned short)(r >> 16);
}

__device__ __forceinline__ void gload_lds16(const void* g, void* l) {
  __builtin_amdgcn_global_load_lds((const __attribute__((address_space(1))) void*)g,
                                   (__attribute__((address_space(3))) void*)l, 16, 0, 0);
}

// read one 16B MFMA fragment from a 128B-row LDS tile with XOR swizzle
__device__ __forceinline__ bf16x8 lds_frag(const char* base, int row, int bir) {
  int off = (row << 7) + bir;
  off ^= (row & 7) << 4;
  return *(const bf16x8*)(base + off);
}

// pack two f32 to packed bf16 (lo = a, hi = b), RTNE
__device__ __forceinline__ int cvtpk_bf16(float a, float b) {
  int r; asm("v_cvt_pk_bf16_f32 %0, %1, %2" : "=v"(r) : "v"(a), "v"(b)); return r;
}

// swap a's upper-lane-half with b's lower-lane-half (v_permlane32_swap_b32)
__device__ __forceinline__ void plswap(int& a, int& b) {
#if __has_builtin(__builtin_amdgcn_permlane32_swap)
  i32x2 r = __builtin_amdgcn_permlane32_swap(a, b, false, false);
  a = r[0]; b = r[1];
#else
  asm volatile("s_nop 1\n\tv_permlane32_swap_b32 %0, %1" : "+v"(a), "+v"(b));
#endif
}

// ---------------- elementwise fp32 -> bf16 ----------------
__global__ __launch_bounds__(256) void k_cvt(const float* __restrict__ src,
                                             unsigned short* __restrict__ dst, int n) {
  int i = (blockIdx.x * 256 + threadIdx.x) * 8;
  if (i >= n) return;
  fl4 a = *(const fl4*)(src + i);
  fl4 b = *(const fl4*)(src + i + 4);
  u16x8 o;
  o[0] = f2bf_bits(a[0]); o[1] = f2bf_bits(a[1]); o[2] = f2bf_bits(a[2]); o[3] = f2bf_bits(a[3]);
  o[4] = f2bf_bits(b[0]); o[5] = f2bf_bits(b[1]); o[6] = f2bf_bits(b[2]); o[7] = f2bf_bits(b[3]);
  *(u16x8*)(dst + i) = o;
}

// ---------------- transpose + convert, both weights in one launch ----------------
// blockIdx.x < 48: W_qkv [1024][3072] -> [3072][1024]; else W_proj [1024][1024] -> [1024][1024]
__global__ __launch_bounds__(256) void k_tcvt2(const float* __restrict__ wqkv,
                                               unsigned short* __restrict__ dqkv,
                                               const float* __restrict__ wproj,
                                               unsigned short* __restrict__ dproj) {
  __shared__ float tile[64][65];
  const int bx = blockIdx.x;
  const float* src; unsigned short* dst; int NCOL, nt;
  if (bx < 48) { src = wqkv; dst = dqkv; NCOL = 3072; nt = bx * 64; }
  else         { src = wproj; dst = dproj; NCOL = 1024; nt = (bx - 48) * 64; }
  const int kt = blockIdx.y * 64;
  const int t = threadIdx.x;
  {
    int r = t >> 2, c0 = (t & 3) * 16;
    const float* s = src + (size_t)(kt + r) * NCOL + nt + c0;
    #pragma unroll
    for (int j = 0; j < 4; ++j) {
      fl4 v = *(const fl4*)(s + j * 4);
      tile[r][c0 + j * 4 + 0] = v[0]; tile[r][c0 + j * 4 + 1] = v[1];
      tile[r][c0 + j * 4 + 2] = v[2]; tile[r][c0 + j * 4 + 3] = v[3];
    }
  }
  __syncthreads();
  {
    int n = t >> 2, kc = (t & 3) * 16;
    unsigned short* d = dst + (size_t)(nt + n) * 1024 + kt + kc;
    u16x8 o0, o1;
    #pragma unroll
    for (int j = 0; j < 8; ++j) o0[j] = f2bf_bits(tile[kc + j][n]);
    #pragma unroll
    for (int j = 0; j < 8; ++j) o1[j] = f2bf_bits(tile[kc + 8 + j][n]);
    *(u16x8*)d = o0;
    *(u16x8*)(d + 8) = o1;
  }
}

// ---------------- bf16 GEMM: C[M][Ncols] = A[M][1024] * Bt[Ncols][1024]^T ----------------
// MODE 0: QKV epilogue (q scaled by scale*log2e, k, v^T scatter); MODE 1: proj + bias, fp32
template <int MODE>
__global__ __launch_bounds__(256) void k_gemm(const unsigned short* __restrict__ A,
                                              const unsigned short* __restrict__ Bt,
                                              unsigned short* __restrict__ qp,
                                              unsigned short* __restrict__ kp,
                                              unsigned short* __restrict__ vtp,
                                              const float* __restrict__ bias,
                                              float* __restrict__ outp) {
  __shared__ char lA[16384], lB[16384];
  const int tid = threadIdx.x, lane = tid & 63, w = tid >> 6;
  const int wm = w >> 1, wn = w & 1;
  const int m0 = blockIdx.y * 128, n0 = blockIdx.x * 128;
  const char* Ab = (const char*)A + (size_t)m0 * 2048;
  const char* Bb = (const char*)Bt + (size_t)n0 * 2048;

  f32x4 acc[4][4];
  #pragma unroll
  for (int mi = 0; mi < 4; ++mi)
    #pragma unroll
    for (int ni = 0; ni < 4; ++ni) acc[mi][ni] = f32x4{0.f, 0.f, 0.f, 0.f};

  for (int kt = 0; kt < 16; ++kt) {
    #pragma unroll
    for (int i = 0; i < 4; ++i) {
      int c = i * 256 + tid;
      int row = c >> 3, cc = c & 7, ccs = cc ^ (row & 7);
      char* dstA = lA + (i * 256 + w * 64) * 16;
      char* dstB = lB + (i * 256 + w * 64) * 16;
      gload_lds16(Ab + (size_t)row * 2048 + kt * 128 + ccs * 16, dstA);
      gload_lds16(Bb + (size_t)row * 2048 + kt * 128 + ccs * 16, dstB);
    }
    __syncthreads();
    #pragma unroll
    for (int ks = 0; ks < 2; ++ks) {
      bf16x8 af[4], bfv[4];
      #pragma unroll
      for (int mi = 0; mi < 4; ++mi)
        af[mi] = lds_frag(lA, wm * 64 + mi * 16 + (lane & 15), ks * 64 + ((lane >> 4) << 4));
      #pragma unroll
      for (int ni = 0; ni < 4; ++ni)
        bfv[ni] = lds_frag(lB, wn * 64 + ni * 16 + (lane & 15), ks * 64 + ((lane >> 4) << 4));
      #pragma unroll
      for (int mi = 0; mi < 4; ++mi)
        #pragma unroll
        for (int ni = 0; ni < 4; ++ni)
          acc[mi][ni] = MFMA16(af[mi], bfv[ni], acc[mi][ni]);
    }
    __syncthreads();
  }

  if (MODE == 0) {
    #pragma unroll
    for (int mi = 0; mi < 4; ++mi) {
      int row0 = m0 + wm * 64 + mi * 16 + ((lane >> 4) << 2);
      int bb = row0 >> 10, nn0 = row0 & 1023;
      #pragma unroll
      for (int ni = 0; ni < 4; ++ni) {
        int col = n0 + wn * 64 + ni * 16 + (lane & 15);
        int tt = col >> 10, rem = col & 1023, h = rem >> 6, d = rem & 63;
        f32x4 a = acc[mi][ni];
        if (tt == 2) {
          u16x4 pv;
          pv[0] = f2bf_bits(a[0]); pv[1] = f2bf_bits(a[1]);
          pv[2] = f2bf_bits(a[2]); pv[3] = f2bf_bits(a[3]);
          *(u16x4*)(vtp + (((size_t)(bb * 16 + h) * 64 + d) << 10) + nn0) = pv;
        } else {
          unsigned short* dst = (tt == 0) ? qp : kp;
          // q pre-scaled by scale*log2e so attention scores land in exp2 domain
          float sc = (tt == 0) ? 0.18033688f : 1.0f;
          size_t base = ((size_t)(bb * 16 + h)) << 16;
          #pragma unroll
          for (int r = 0; r < 4; ++r)
            dst[base + (size_t)(nn0 + r) * 64 + d] = f2bf_bits(a[r] * sc);
        }
      }
    }
  } else {
    #pragma unroll
    for (int mi = 0; mi < 4; ++mi) {
      int row0 = m0 + wm * 64 + mi * 16 + ((lane >> 4) << 2);
      #pragma unroll
      for (int ni = 0; ni < 4; ++ni) {
        int col = n0 + wn * 64 + ni * 16 + (lane & 15);
        float bv = bias[col];
        f32x4 a = acc[mi][ni];
        #pragma unroll
        for (int r = 0; r < 4; ++r)
          outp[(size_t)(row0 + r) * 1024 + col] = a[r] + bv;
      }
    }
  }
}

// ---------------- flash attention: 8-wave blocks, 3-buffer counted-vmcnt pipeline ----------------
// r11 structure; VALU-trimmed: q pre-scaled (no per-elem fma), full exp2-domain bias folded
// into the acc-INIT MFMA (no per-step acc zeroing), raw v_exp_f32.
// 512 blocks = 64 heads x 8 q-chunks (128 rows). 8 waves = 4 q-subchunks x 2 key-pairs.
// Buffer layout (16KB): [KA 4K][KB 4K][VA 4K][VB 4K]
//   K tile: 32 rows x 128B, slot s at row r holds global chunk s^(r&7)
//   V tile: 64 rows x 64B,  slot s at row r holds global chunk s^((r>>1)&3)
__global__ __launch_bounds__(512, 4) void k_attn(const unsigned short* __restrict__ qp,
                                                 const unsigned short* __restrict__ kp,
                                                 const unsigned short* __restrict__ vtp,
                                                 const float* __restrict__ mask,
                                                 unsigned short* __restrict__ aop) {
  __shared__ __align__(16) char lds[49152];
  const int tid = threadIdx.x, lane = tid & 63, w = tid >> 6;
  const int hi = lane >> 5, lq = lane & 31;
  const int pair = w >> 2, qsub = w & 3;
  // XCD swizzle: all 8 q-chunk blocks of a head on one XCD; 8 heads/XCD (~3MB < 4MB L2)
  const int g = blockIdx.x;
  const int bh = (g & 7) * 8 + ((g >> 6) & 7);
  const int qc = (g >> 3) & 7;
  const int b = bh >> 4, h = bh & 15;
  const char* kb = (const char*)(kp + ((size_t)bh << 16));
  const char* vb = (const char*)(vtp + ((size_t)bh << 16));
  const unsigned short* qh = qp + ((size_t)bh << 16);
  const float* mrow = mask + b * 1024 + pair * 512;
  const int q0 = qc * 128 + qsub * 32;

  // ---- staging addresses: thread covers K chunk tid and V chunk tid (512 each) ----
  const int kpk = tid >> 8, krow = (tid >> 3) & 31, kslot = tid & 7;
  const char* gK = kb + (size_t)kpk * 65536 + (size_t)krow * 128
                   + ((kslot ^ (krow & 7)) * 16);                    // + t*4096
  const int vpk = tid >> 8, vrow = (tid >> 2) & 63, vslot = tid & 3;
  const char* gV = vb + (size_t)vpk * 1024 + (size_t)vrow * 2048
                   + ((vslot ^ ((vrow >> 1) & 3)) * 16);             // + t*64
  char* const dK = lds + tid * 16;          // + buf*16384
  char* const dV = lds + 8192 + tid * 16;   // + buf*16384

  // ---- hoisted fragment-read offsets (within pair's 4KB region) ----
  int kfo[4], vfo[4];
  #pragma unroll
  for (int dc = 0; dc < 4; ++dc)
    kfo[dc] = lq * 128 + (((dc << 1) | hi) ^ (lq & 7)) * 16;
  #pragma unroll
  for (int ks = 0; ks < 2; ++ks)
    #pragma unroll
    for (int nb = 0; nb < 2; ++nb) {
      int row = nb * 32 + lq;
      vfo[ks * 2 + nb] = row * 64 + (((ks << 1) | hi) ^ ((row >> 1) & 3)) * 16;
    }

  // ---- hoist ALL mask handling: per-step bias-MFMA A-words, FULL exp2-domain bias ----
  // bias(key) = ((1-m)*(-5) - 4) * log2e = m*7.2134752 - 12.9842554; per-key-uniform part
  // cancels in normalization, so bf16 rounding of the constant is harmless.
  int bws[16];
  #pragma unroll
  for (int t2 = 0; t2 < 16; ++t2) {
    float mv = mrow[t2 * 32 + lq];
    bws[t2] = (hi == 0) ? (int)f2bf_bits(fmaf(mv, 7.2134752f, -12.9842554f)) : 0;
  }

  // Q B-frags: B[kd = dc*16 + hi*8 + j][q = lq]  (q pre-scaled by scale*log2e in k_gemm<0>)
  bf16x8 qB[4];
  #pragma unroll
  for (int dc = 0; dc < 4; ++dc)
    qB[dc] = *(const bf16x8*)(qh + (q0 + lq) * 64 + dc * 16 + hi * 8);

  // ones B-frag for the bias MFMA: B[0][q] = 1
  i32x4 onesw = {hi == 0 ? 0x3F80 : 0, 0, 0, 0};
  const bf16x8 onesB = __builtin_bit_cast(bf16x8, onesw);

  // persistent zero accumulator (C-in for the per-step bias-init MFMA)
  f32x16 Z16;
  #pragma unroll
  for (int i = 0; i < 16; ++i) Z16[i] = 0.f;

  f32x16 O0, O1;
  #pragma unroll
  for (int i = 0; i < 16; ++i) { O0[i] = 0.f; O1[i] = 0.f; }
  float lsum = 0.f;

#define STAGE(BUF, T)                                                          \
  do {                                                                         \
    gload_lds16(gK + (T) * 4096, dK + (BUF) * 16384);                          \
    gload_lds16(gV + (T) * 64,   dV + (BUF) * 16384);                          \
  } while (0)

#define VMCNT(N) asm volatile("s_waitcnt vmcnt(" #N ")" ::: "memory")

#define STEP(BUF, T, N)                                                        \
  do {                                                                         \
    VMCNT(N);                                                                  \
    __builtin_amdgcn_s_barrier();                                              \
    if ((T) + 2 <= 15) STAGE(((T) + 2) % 3, (T) + 2);                          \
    const char* K = lds + (BUF) * 16384 + pair * 4096;                         \
    const char* V = lds + (BUF) * 16384 + 8192 + pair * 4096;                  \
    f32x16 acc;                                                                \
    {                                                                          \
      i32x4 bwv = {bws[T], 0, 0, 0};                                           \
      acc = MFMA32(__builtin_bit_cast(bf16x8, bwv), onesB, Z16);               \
    }                                                                          \
    __builtin_amdgcn_s_setprio(1);                                             \
    _Pragma("unroll") for (int dc = 0; dc < 4; ++dc) {                         \
      bf16x8 kf = *(const bf16x8*)(K + kfo[dc]);                               \
      acc = MFMA32(kf, qB[dc], acc);                                           \
    }                                                                          \
    __builtin_amdgcn_s_setprio(0);                                             \
    float p[16];                                                               \
    _Pragma("unroll") for (int r = 0; r < 16; ++r) {                           \
      p[r] = EXP2R(acc[r]);                                                    \
      lsum += p[r];                                                            \
    }                                                                          \
    int X0 = cvtpk_bf16(p[0], p[1]),   X1 = cvtpk_bf16(p[2], p[3]);            \
    int Y0 = cvtpk_bf16(p[4], p[5]),   Y1 = cvtpk_bf16(p[6], p[7]);            \
    int Z0 = cvtpk_bf16(p[8], p[9]),   Z1 = cvtpk_bf16(p[10], p[11]);          \
    int W0 = cvtpk_bf16(p[12], p[13]), W1 = cvtpk_bf16(p[14], p[15]);          \
    plswap(X0, Y0); plswap(X1, Y1);                                            \
    plswap(Z0, W0); plswap(Z1, W1);                                            \
    i32x4 pa0v = {X0, X1, Y0, Y1};                                             \
    i32x4 pa1v = {Z0, Z1, W0, W1};                                             \
    const bf16x8 PA0 = __builtin_bit_cast(bf16x8, pa0v);                       \
    const bf16x8 PA1 = __builtin_bit_cast(bf16x8, pa1v);                       \
    bf16x8 va0 = *(const bf16x8*)(V + vfo[0]);                                 \
    bf16x8 va1 = *(const bf16x8*)(V + vfo[1]);                                 \
    bf16x8 vb0 = *(const bf16x8*)(V + vfo[2]);                                 \
    bf16x8 vb1 = *(const bf16x8*)(V + vfo[3]);                                 \
    __builtin_amdgcn_s_setprio(1);                                             \
    O0 = MFMA32(PA0, va0, O0);                                                 \
    O1 = MFMA32(PA0, va1, O1);                                                 \
    O0 = MFMA32(PA1, vb0, O0);                                                 \
    O1 = MFMA32(PA1, vb1, O1);                                                 \
    __builtin_amdgcn_s_setprio(0);                                             \
  } while (0)

  STAGE(0, 0);
  STAGE(1, 1);
  STEP(0, 0, 2);  STEP(1, 1, 2);  STEP(2, 2, 2);  STEP(0, 3, 2);
  STEP(1, 4, 2);  STEP(2, 5, 2);  STEP(0, 6, 2);  STEP(1, 7, 2);
  STEP(2, 8, 2);  STEP(0, 9, 2);  STEP(1, 10, 2); STEP(2, 11, 2);
  STEP(0, 12, 2); STEP(1, 13, 2); STEP(2, 14, 2); STEP(0, 15, 0);
#undef STEP
#undef VMCNT
#undef STAGE

  // ---- combine the two key-halves through LDS, then normalize + store ----
  __syncthreads();
  float tot = lsum + __shfl_xor(lsum, 32);
  float* fx = (float*)lds;
  if (pair == 1) {
    int base = qsub * 64 * 34 + lane * 34;
    #pragma unroll
    for (int r = 0; r < 16; ++r) { fx[base + r] = O0[r]; fx[base + 16 + r] = O1[r]; }
    fx[base + 32] = tot;
  }
  __syncthreads();
  if (pair == 0) {
    int base = qsub * 64 * 34 + lane * 34;
    float invT = 1.0f / (tot + fx[base + 32]);
    #pragma unroll
    for (int r = 0; r < 16; ++r) {
      int qr = (r & 3) + 8 * (r >> 2) + 4 * hi;
      float iv = __shfl(invT, qr);
      float o0 = (O0[r] + fx[base + r]) * iv;
      float o1 = (O1[r] + fx[base + 16 + r]) * iv;
      size_t ob = (size_t)(b * 1024 + q0 + qr) * 1024 + h * 64 + lq;
      aop[ob] = f2bf_bits(o0);
      aop[ob + 32] = f2bf_bits(o1);
    }
  }
}

extern "C" void kernel_launch(void* const* d_in, const int* in_sizes, int n_in,
                              void* d_out, int out_size, void* d_ws, size_t ws_size,
                              hipStream_t stream) {
  const float* x     = (const float*)d_in[0];
  const float* mask  = (const float*)d_in[1];
  const float* wqkv  = (const float*)d_in[2];
  const float* wproj = (const float*)d_in[3];
  const float* bproj = (const float*)d_in[4];
  float* out = (float*)d_out;

  char* ws = (char*)d_ws;
  unsigned short* xb     = (unsigned short*)(ws);                 //  8 MB  x bf16 [4096][1024]
  unsigned short* wqkvt  = (unsigned short*)(ws + 8388608);       //  6 MB  W_qkv^T bf16 [3072][1024]
  unsigned short* wprojt = (unsigned short*)(ws + 14680064);      //  2 MB  W_proj^T bf16 [1024][1024]
  unsigned short* qbuf   = (unsigned short*)(ws + 16777216);      //  8 MB  q [B,H,N,D] (pre-scaled)
  unsigned short* kbuf   = (unsigned short*)(ws + 25165824);      //  8 MB  k [B,H,N,D]
  unsigned short* vtbuf  = (unsigned short*)(ws + 33554432);      //  8 MB  v^T [B,H,D,N]
  unsigned short* aobuf  = (unsigned short*)(ws + 41943040);      //  8 MB  attn out bf16 [4096][1024]

  k_cvt<<<dim3(2048), dim3(256), 0, stream>>>(x, xb, 4194304);
  k_tcvt2<<<dim3(64, 16), dim3(256), 0, stream>>>(wqkv, wqkvt, wproj, wprojt);
  k_gemm<0><<<dim3(24, 32), dim3(256), 0, stream>>>(xb, wqkvt, qbuf, kbuf, vtbuf, nullptr, nullptr);
  k_attn<<<dim3(512), dim3(512), 0, stream>>>(qbuf, kbuf, vtbuf, mask, aobuf);
  k_gemm<1><<<dim3(8, 32), dim3(256), 0, stream>>>(aobuf, wprojt, nullptr, nullptr, nullptr, bproj, out);
}

// Round 13
// 95.352 us; speedup vs baseline: 1.1345x; 1.1345x over previous
//
#include <hip/hip_runtime.h>

typedef __attribute__((ext_vector_type(8))) short bf16x8;
typedef __attribute__((ext_vector_type(4))) float f32x4;
typedef __attribute__((ext_vector_type(16))) float f32x16;
typedef __attribute__((ext_vector_type(4))) float fl4;
typedef __attribute__((ext_vector_type(8))) unsigned short u16x8;
typedef __attribute__((ext_vector_type(4))) unsigned short u16x4;
typedef __attribute__((ext_vector_type(2))) int i32x2;
typedef __attribute__((ext_vector_type(4))) int i32x4;

#define MFMA16(A,B,C) __builtin_amdgcn_mfma_f32_16x16x32_bf16((A),(B),(C),0,0,0)
#define MFMA32(A,B,C) __builtin_amdgcn_mfma_f32_32x32x16_bf16((A),(B),(C),0,0,0)

#if __has_builtin(__builtin_amdgcn_exp2f)
#define EXP2R(x) __builtin_amdgcn_exp2f(x)
#else
#define EXP2R(x) exp2f(x)
#endif

__device__ __forceinline__ unsigned short f2bf_bits(float x) {
  union { float f; unsigned u; } v; v.f = x;
  unsigned r = v.u + 0x7fffu + ((v.u >> 16) & 1u);  // RTNE
  return (unsigned short)(r >> 16);
}

__device__ __forceinline__ void gload_lds16(const void* g, void* l) {
  __builtin_amdgcn_global_load_lds((const __attribute__((address_space(1))) void*)g,
                                   (__attribute__((address_space(3))) void*)l, 16, 0, 0);
}

// read one 16B MFMA fragment from a 128B-row LDS tile with XOR swizzle
__device__ __forceinline__ bf16x8 lds_frag(const char* base, int row, int bir) {
  int off = (row << 7) + bir;
  off ^= (row & 7) << 4;
  return *(const bf16x8*)(base + off);
}

// pack two f32 to packed bf16 (lo = a, hi = b), RTNE
__device__ __forceinline__ int cvtpk_bf16(float a, float b) {
  int r; asm("v_cvt_pk_bf16_f32 %0, %1, %2" : "=v"(r) : "v"(a), "v"(b)); return r;
}

// swap a's upper-lane-half with b's lower-lane-half (v_permlane32_swap_b32)
__device__ __forceinline__ void plswap(int& a, int& b) {
#if __has_builtin(__builtin_amdgcn_permlane32_swap)
  i32x2 r = __builtin_amdgcn_permlane32_swap(a, b, false, false);
  a = r[0]; b = r[1];
#else
  asm volatile("s_nop 1\n\tv_permlane32_swap_b32 %0, %1" : "+v"(a), "+v"(b));
#endif
}

// ---------------- fused prep: x fp32->bf16 (blocks 0-2047) + weight transpose-convert ----------------
// blocks 2048-3071: idx = bid-2048; bx = idx&63, by = idx>>6 (kt = by*64)
//   bx < 48: W_qkv [1024][3072] -> [3072][1024]; q-columns (bx<16) pre-scaled by scale*log2e
//   bx >= 48: W_proj [1024][1024] -> [1024][1024]
__global__ __launch_bounds__(256) void k_prep(const float* __restrict__ x,
                                              unsigned short* __restrict__ xb,
                                              const float* __restrict__ wqkv,
                                              unsigned short* __restrict__ dqkv,
                                              const float* __restrict__ wproj,
                                              unsigned short* __restrict__ dproj) {
  __shared__ float tile[64][65];
  const int bid = blockIdx.x;
  const int t = threadIdx.x;
  if (bid < 2048) {
    int i = (bid * 256 + t) * 8;
    fl4 a = *(const fl4*)(x + i);
    fl4 b = *(const fl4*)(x + i + 4);
    u16x8 o;
    o[0] = f2bf_bits(a[0]); o[1] = f2bf_bits(a[1]); o[2] = f2bf_bits(a[2]); o[3] = f2bf_bits(a[3]);
    o[4] = f2bf_bits(b[0]); o[5] = f2bf_bits(b[1]); o[6] = f2bf_bits(b[2]); o[7] = f2bf_bits(b[3]);
    *(u16x8*)(xb + i) = o;
    return;
  }
  const int idx = bid - 2048;
  const int bx = idx & 63, by = idx >> 6;
  const float* src; unsigned short* dst; int NCOL, nt;
  if (bx < 48) { src = wqkv; dst = dqkv; NCOL = 3072; nt = bx * 64; }
  else         { src = wproj; dst = dproj; NCOL = 1024; nt = (bx - 48) * 64; }
  const float sc = (bx < 16) ? 0.18033688f : 1.0f;   // q-columns: fold scale*log2e into W
  const int kt = by * 64;
  {
    int r = t >> 2, c0 = (t & 3) * 16;
    const float* s = src + (size_t)(kt + r) * NCOL + nt + c0;
    #pragma unroll
    for (int j = 0; j < 4; ++j) {
      fl4 v = *(const fl4*)(s + j * 4);
      tile[r][c0 + j * 4 + 0] = v[0]; tile[r][c0 + j * 4 + 1] = v[1];
      tile[r][c0 + j * 4 + 2] = v[2]; tile[r][c0 + j * 4 + 3] = v[3];
    }
  }
  __syncthreads();
  {
    int n = t >> 2, kc = (t & 3) * 16;
    unsigned short* d = dst + (size_t)(nt + n) * 1024 + kt + kc;
    u16x8 o0, o1;
    #pragma unroll
    for (int j = 0; j < 8; ++j) o0[j] = f2bf_bits(tile[kc + j][n] * sc);
    #pragma unroll
    for (int j = 0; j < 8; ++j) o1[j] = f2bf_bits(tile[kc + 8 + j][n] * sc);
    *(u16x8*)d = o0;
    *(u16x8*)(d + 8) = o1;
  }
}

// ---------------- bf16 GEMM: C[M][Ncols] = A[M][1024] * Bt[Ncols][1024]^T ----------------
// MODE 0: QKV epilogue (q/k/v^T scatter; q pre-scaled via W); MODE 1: proj + bias, fp32
template <int MODE>
__global__ __launch_bounds__(256) void k_gemm(const unsigned short* __restrict__ A,
                                              const unsigned short* __restrict__ Bt,
                                              unsigned short* __restrict__ qp,
                                              unsigned short* __restrict__ kp,
                                              unsigned short* __restrict__ vtp,
                                              const float* __restrict__ bias,
                                              float* __restrict__ outp) {
  __shared__ char lA[16384], lB[16384];
  const int tid = threadIdx.x, lane = tid & 63, w = tid >> 6;
  const int wm = w >> 1, wn = w & 1;
  const int m0 = blockIdx.y * 128, n0 = blockIdx.x * 128;
  const char* Ab = (const char*)A + (size_t)m0 * 2048;
  const char* Bb = (const char*)Bt + (size_t)n0 * 2048;

  f32x4 acc[4][4];
  #pragma unroll
  for (int mi = 0; mi < 4; ++mi)
    #pragma unroll
    for (int ni = 0; ni < 4; ++ni) acc[mi][ni] = f32x4{0.f, 0.f, 0.f, 0.f};

  for (int kt = 0; kt < 16; ++kt) {
    #pragma unroll
    for (int i = 0; i < 4; ++i) {
      int c = i * 256 + tid;
      int row = c >> 3, cc = c & 7, ccs = cc ^ (row & 7);
      char* dstA = lA + (i * 256 + w * 64) * 16;
      char* dstB = lB + (i * 256 + w * 64) * 16;
      gload_lds16(Ab + (size_t)row * 2048 + kt * 128 + ccs * 16, dstA);
      gload_lds16(Bb + (size_t)row * 2048 + kt * 128 + ccs * 16, dstB);
    }
    __syncthreads();
    #pragma unroll
    for (int ks = 0; ks < 2; ++ks) {
      bf16x8 af[4], bfv[4];
      #pragma unroll
      for (int mi = 0; mi < 4; ++mi)
        af[mi] = lds_frag(lA, wm * 64 + mi * 16 + (lane & 15), ks * 64 + ((lane >> 4) << 4));
      #pragma unroll
      for (int ni = 0; ni < 4; ++ni)
        bfv[ni] = lds_frag(lB, wn * 64 + ni * 16 + (lane & 15), ks * 64 + ((lane >> 4) << 4));
      #pragma unroll
      for (int mi = 0; mi < 4; ++mi)
        #pragma unroll
        for (int ni = 0; ni < 4; ++ni)
          acc[mi][ni] = MFMA16(af[mi], bfv[ni], acc[mi][ni]);
    }
    __syncthreads();
  }

  if (MODE == 0) {
    #pragma unroll
    for (int mi = 0; mi < 4; ++mi) {
      int row0 = m0 + wm * 64 + mi * 16 + ((lane >> 4) << 2);
      int bb = row0 >> 10, nn0 = row0 & 1023;
      #pragma unroll
      for (int ni = 0; ni < 4; ++ni) {
        int col = n0 + wn * 64 + ni * 16 + (lane & 15);
        int tt = col >> 10, rem = col & 1023, h = rem >> 6, d = rem & 63;
        f32x4 a = acc[mi][ni];
        if (tt == 2) {
          u16x4 pv;
          pv[0] = f2bf_bits(a[0]); pv[1] = f2bf_bits(a[1]);
          pv[2] = f2bf_bits(a[2]); pv[3] = f2bf_bits(a[3]);
          *(u16x4*)(vtp + (((size_t)(bb * 16 + h) * 64 + d) << 10) + nn0) = pv;
        } else {
          unsigned short* dst = (tt == 0) ? qp : kp;
          size_t base = ((size_t)(bb * 16 + h)) << 16;
          #pragma unroll
          for (int r = 0; r < 4; ++r)
            dst[base + (size_t)(nn0 + r) * 64 + d] = f2bf_bits(a[r]);
        }
      }
    }
  } else {
    #pragma unroll
    for (int mi = 0; mi < 4; ++mi) {
      int row0 = m0 + wm * 64 + mi * 16 + ((lane >> 4) << 2);
      #pragma unroll
      for (int ni = 0; ni < 4; ++ni) {
        int col = n0 + wn * 64 + ni * 16 + (lane & 15);
        float bv = bias[col];
        f32x4 a = acc[mi][ni];
        #pragma unroll
        for (int r = 0; r < 4; ++r)
          outp[(size_t)(row0 + r) * 1024 + col] = a[r] + bv;
      }
    }
  }
}

// ---------------- flash attention: 8-wave blocks, 3-buffer counted-vmcnt pipeline ----------------
// r12 structure: q pre-scaled (via W), full exp2-domain bias folded into the acc-INIT MFMA,
// raw v_exp_f32. 512 blocks = 64 heads x 8 q-chunks (128 rows). 8 waves = 4 q-subchunks x
// 2 key-pairs. Buffer layout (16KB): [KA 4K][KB 4K][VA 4K][VB 4K]
//   K tile: 32 rows x 128B, slot s at row r holds global chunk s^(r&7)
//   V tile: 64 rows x 64B,  slot s at row r holds global chunk s^((r>>1)&3)
__global__ __launch_bounds__(512, 4) void k_attn(const unsigned short* __restrict__ qp,
                                                 const unsigned short* __restrict__ kp,
                                                 const unsigned short* __restrict__ vtp,
                                                 const float* __restrict__ mask,
                                                 unsigned short* __restrict__ aop) {
  __shared__ __align__(16) char lds[49152];
  const int tid = threadIdx.x, lane = tid & 63, w = tid >> 6;
  const int hi = lane >> 5, lq = lane & 31;
  const int pair = w >> 2, qsub = w & 3;
  // XCD swizzle: all 8 q-chunk blocks of a head on one XCD; 8 heads/XCD (~3MB < 4MB L2)
  const int g = blockIdx.x;
  const int bh = (g & 7) * 8 + ((g >> 6) & 7);
  const int qc = (g >> 3) & 7;
  const int b = bh >> 4, h = bh & 15;
  const char* kb = (const char*)(kp + ((size_t)bh << 16));
  const char* vb = (const char*)(vtp + ((size_t)bh << 16));
  const unsigned short* qh = qp + ((size_t)bh << 16);
  const float* mrow = mask + b * 1024 + pair * 512;
  const int q0 = qc * 128 + qsub * 32;

  // ---- staging addresses: thread covers K chunk tid and V chunk tid (512 each) ----
  const int kpk = tid >> 8, krow = (tid >> 3) & 31, kslot = tid & 7;
  const char* gK = kb + (size_t)kpk * 65536 + (size_t)krow * 128
                   + ((kslot ^ (krow & 7)) * 16);                    // + t*4096
  const int vpk = tid >> 8, vrow = (tid >> 2) & 63, vslot = tid & 3;
  const char* gV = vb + (size_t)vpk * 1024 + (size_t)vrow * 2048
                   + ((vslot ^ ((vrow >> 1) & 3)) * 16);             // + t*64
  char* const dK = lds + tid * 16;          // + buf*16384
  char* const dV = lds + 8192 + tid * 16;   // + buf*16384

  // ---- hoisted fragment-read offsets (within pair's 4KB region) ----
  int kfo[4], vfo[4];
  #pragma unroll
  for (int dc = 0; dc < 4; ++dc)
    kfo[dc] = lq * 128 + (((dc << 1) | hi) ^ (lq & 7)) * 16;
  #pragma unroll
  for (int ks = 0; ks < 2; ++ks)
    #pragma unroll
    for (int nb = 0; nb < 2; ++nb) {
      int row = nb * 32 + lq;
      vfo[ks * 2 + nb] = row * 64 + (((ks << 1) | hi) ^ ((row >> 1) & 3)) * 16;
    }

  // ---- hoist ALL mask handling: per-step bias-MFMA A-words, FULL exp2-domain bias ----
  // bias(key) = ((1-m)*(-5) - 4) * log2e = m*7.2134752 - 12.9842554; per-key-uniform part
  // cancels in normalization, so bf16 rounding of the constant is harmless.
  int bws[16];
  #pragma unroll
  for (int t2 = 0; t2 < 16; ++t2) {
    float mv = mrow[t2 * 32 + lq];
    bws[t2] = (hi == 0) ? (int)f2bf_bits(fmaf(mv, 7.2134752f, -12.9842554f)) : 0;
  }

  // Q B-frags: B[kd = dc*16 + hi*8 + j][q = lq]  (q pre-scaled by scale*log2e via W)
  bf16x8 qB[4];
  #pragma unroll
  for (int dc = 0; dc < 4; ++dc)
    qB[dc] = *(const bf16x8*)(qh + (q0 + lq) * 64 + dc * 16 + hi * 8);

  // ones B-frag for the bias MFMA: B[0][q] = 1
  i32x4 onesw = {hi == 0 ? 0x3F80 : 0, 0, 0, 0};
  const bf16x8 onesB = __builtin_bit_cast(bf16x8, onesw);

  // persistent zero accumulator (C-in for the per-step bias-init MFMA)
  f32x16 Z16;
  #pragma unroll
  for (int i = 0; i < 16; ++i) Z16[i] = 0.f;

  f32x16 O0, O1;
  #pragma unroll
  for (int i = 0; i < 16; ++i) { O0[i] = 0.f; O1[i] = 0.f; }
  float lsum = 0.f;

#define STAGE(BUF, T)                                                          \
  do {                                                                         \
    gload_lds16(gK + (T) * 4096, dK + (BUF) * 16384);                          \
    gload_lds16(gV + (T) * 64,   dV + (BUF) * 16384);                          \
  } while (0)

#define VMCNT(N) asm volatile("s_waitcnt vmcnt(" #N ")" ::: "memory")

#define STEP(BUF, T, N)                                                        \
  do {                                                                         \
    VMCNT(N);                                                                  \
    __builtin_amdgcn_s_barrier();                                              \
    if ((T) + 2 <= 15) STAGE(((T) + 2) % 3, (T) + 2);                          \
    const char* K = lds + (BUF) * 16384 + pair * 4096;                         \
    const char* V = lds + (BUF) * 16384 + 8192 + pair * 4096;                  \
    f32x16 acc;                                                                \
    {                                                                          \
      i32x4 bwv = {bws[T], 0, 0, 0};                                           \
      acc = MFMA32(__builtin_bit_cast(bf16x8, bwv), onesB, Z16);               \
    }                                                                          \
    __builtin_amdgcn_s_setprio(1);                                             \
    _Pragma("unroll") for (int dc = 0; dc < 4; ++dc) {                         \
      bf16x8 kf = *(const bf16x8*)(K + kfo[dc]);                               \
      acc = MFMA32(kf, qB[dc], acc);                                           \
    }                                                                          \
    __builtin_amdgcn_s_setprio(0);                                             \
    float p[16];                                                               \
    _Pragma("unroll") for (int r = 0; r < 16; ++r) {                           \
      p[r] = EXP2R(acc[r]);                                                    \
      lsum += p[r];                                                            \
    }                                                                          \
    int X0 = cvtpk_bf16(p[0], p[1]),   X1 = cvtpk_bf16(p[2], p[3]);            \
    int Y0 = cvtpk_bf16(p[4], p[5]),   Y1 = cvtpk_bf16(p[6], p[7]);            \
    int Z0 = cvtpk_bf16(p[8], p[9]),   Z1 = cvtpk_bf16(p[10], p[11]);          \
    int W0 = cvtpk_bf16(p[12], p[13]), W1 = cvtpk_bf16(p[14], p[15]);          \
    plswap(X0, Y0); plswap(X1, Y1);                                            \
    plswap(Z0, W0); plswap(Z1, W1);                                            \
    i32x4 pa0v = {X0, X1, Y0, Y1};                                             \
    i32x4 pa1v = {Z0, Z1, W0, W1};                                             \
    const bf16x8 PA0 = __builtin_bit_cast(bf16x8, pa0v);                       \
    const bf16x8 PA1 = __builtin_bit_cast(bf16x8, pa1v);                       \
    bf16x8 va0 = *(const bf16x8*)(V + vfo[0]);                                 \
    bf16x8 va1 = *(const bf16x8*)(V + vfo[1]);                                 \
    bf16x8 vb0 = *(const bf16x8*)(V + vfo[2]);                                 \
    bf16x8 vb1 = *(const bf16x8*)(V + vfo[3]);                                 \
    __builtin_amdgcn_s_setprio(1);                                             \
    O0 = MFMA32(PA0, va0, O0);                                                 \
    O1 = MFMA32(PA0, va1, O1);                                                 \
    O0 = MFMA32(PA1, vb0, O0);                                                 \
    O1 = MFMA32(PA1, vb1, O1);                                                 \
    __builtin_amdgcn_s_setprio(0);                                             \
  } while (0)

  STAGE(0, 0);
  STAGE(1, 1);
  STEP(0, 0, 2);  STEP(1, 1, 2);  STEP(2, 2, 2);  STEP(0, 3, 2);
  STEP(1, 4, 2);  STEP(2, 5, 2);  STEP(0, 6, 2);  STEP(1, 7, 2);
  STEP(2, 8, 2);  STEP(0, 9, 2);  STEP(1, 10, 2); STEP(2, 11, 2);
  STEP(0, 12, 2); STEP(1, 13, 2); STEP(2, 14, 2); STEP(0, 15, 0);
#undef STEP
#undef VMCNT
#undef STAGE

  // ---- combine the two key-halves through LDS, then normalize + store ----
  __syncthreads();
  float tot = lsum + __shfl_xor(lsum, 32);
  float* fx = (float*)lds;
  if (pair == 1) {
    int base = qsub * 64 * 34 + lane * 34;
    #pragma unroll
    for (int r = 0; r < 16; ++r) { fx[base + r] = O0[r]; fx[base + 16 + r] = O1[r]; }
    fx[base + 32] = tot;
  }
  __syncthreads();
  if (pair == 0) {
    int base = qsub * 64 * 34 + lane * 34;
    float invT = 1.0f / (tot + fx[base + 32]);
    #pragma unroll
    for (int r = 0; r < 16; ++r) {
      int qr = (r & 3) + 8 * (r >> 2) + 4 * hi;
      float iv = __shfl(invT, qr);
      float o0 = (O0[r] + fx[base + r]) * iv;
      float o1 = (O1[r] + fx[base + 16 + r]) * iv;
      size_t ob = (size_t)(b * 1024 + q0 + qr) * 1024 + h * 64 + lq;
      aop[ob] = f2bf_bits(o0);
      aop[ob + 32] = f2bf_bits(o1);
    }
  }
}

extern "C" void kernel_launch(void* const* d_in, const int* in_sizes, int n_in,
                              void* d_out, int out_size, void* d_ws, size_t ws_size,
                              hipStream_t stream) {
  const float* x     = (const float*)d_in[0];
  const float* mask  = (const float*)d_in[1];
  const float* wqkv  = (const float*)d_in[2];
  const float* wproj = (const float*)d_in[3];
  const float* bproj = (const float*)d_in[4];
  float* out = (float*)d_out;

  char* ws = (char*)d_ws;
  unsigned short* xb     = (unsigned short*)(ws);                 //  8 MB  x bf16 [4096][1024]
  unsigned short* wqkvt  = (unsigned short*)(ws + 8388608);       //  6 MB  W_qkv^T bf16 [3072][1024] (q cols pre-scaled)
  unsigned short* wprojt = (unsigned short*)(ws + 14680064);      //  2 MB  W_proj^T bf16 [1024][1024]
  unsigned short* qbuf   = (unsigned short*)(ws + 16777216);      //  8 MB  q [B,H,N,D] (pre-scaled)
  unsigned short* kbuf   = (unsigned short*)(ws + 25165824);      //  8 MB  k [B,H,N,D]
  unsigned short* vtbuf  = (unsigned short*)(ws + 33554432);      //  8 MB  v^T [B,H,D,N]
  unsigned short* aobuf  = (unsigned short*)(ws + 41943040);      //  8 MB  attn out bf16 [4096][1024]

  k_prep<<<dim3(3072), dim3(256), 0, stream>>>(x, xb, wqkv, wqkvt, wproj, wprojt);
  k_gemm<0><<<dim3(24, 32), dim3(256), 0, stream>>>(xb, wqkvt, qbuf, kbuf, vtbuf, nullptr, nullptr);
  k_attn<<<dim3(512), dim3(512), 0, stream>>>(qbuf, kbuf, vtbuf, mask, aobuf);
  k_gemm<1><<<dim3(8, 32), dim3(256), 0, stream>>>(aobuf, wprojt, nullptr, nullptr, nullptr, bproj, out);
}

// Round 14
// 91.368 us; speedup vs baseline: 1.1839x; 1.0436x over previous
//
#include <hip/hip_runtime.h>

typedef __attribute__((ext_vector_type(8))) short bf16x8;
typedef __attribute__((ext_vector_type(4))) float f32x4;
typedef __attribute__((ext_vector_type(16))) float f32x16;
typedef __attribute__((ext_vector_type(4))) float fl4;
typedef __attribute__((ext_vector_type(8))) unsigned short u16x8;
typedef __attribute__((ext_vector_type(4))) unsigned short u16x4;
typedef __attribute__((ext_vector_type(2))) int i32x2;
typedef __attribute__((ext_vector_type(4))) int i32x4;

#define MFMA16(A,B,C) __builtin_amdgcn_mfma_f32_16x16x32_bf16((A),(B),(C),0,0,0)
#define MFMA32(A,B,C) __builtin_amdgcn_mfma_f32_32x32x16_bf16((A),(B),(C),0,0,0)

#if __has_builtin(__builtin_amdgcn_exp2f)
#define EXP2R(x) __builtin_amdgcn_exp2f(x)
#else
#define EXP2R(x) exp2f(x)
#endif

__device__ __forceinline__ unsigned short f2bf_bits(float x) {
  union { float f; unsigned u; } v; v.f = x;
  unsigned r = v.u + 0x7fffu + ((v.u >> 16) & 1u);  // RTNE
  return (unsigned short)(r >> 16);
}

__device__ __forceinline__ void gload_lds16(const void* g, void* l) {
  __builtin_amdgcn_global_load_lds((const __attribute__((address_space(1))) void*)g,
                                   (__attribute__((address_space(3))) void*)l, 16, 0, 0);
}

// pack two f32 to packed bf16 (lo = a, hi = b), RTNE
__device__ __forceinline__ int cvtpk_bf16(float a, float b) {
  int r; asm("v_cvt_pk_bf16_f32 %0, %1, %2" : "=v"(r) : "v"(a), "v"(b)); return r;
}

// swap a's upper-lane-half with b's lower-lane-half (v_permlane32_swap_b32)
__device__ __forceinline__ void plswap(int& a, int& b) {
#if __has_builtin(__builtin_amdgcn_permlane32_swap)
  i32x2 r = __builtin_amdgcn_permlane32_swap(a, b, false, false);
  a = r[0]; b = r[1];
#else
  asm volatile("s_nop 1\n\tv_permlane32_swap_b32 %0, %1" : "+v"(a), "+v"(b));
#endif
}

// ---------------- fused prep: x fp32->bf16 (blocks 0-2047) + weight transpose-convert ----------------
__global__ __launch_bounds__(256) void k_prep(const float* __restrict__ x,
                                              unsigned short* __restrict__ xb,
                                              const float* __restrict__ wqkv,
                                              unsigned short* __restrict__ dqkv,
                                              const float* __restrict__ wproj,
                                              unsigned short* __restrict__ dproj) {
  __shared__ float tile[64][65];
  const int bid = blockIdx.x;
  const int t = threadIdx.x;
  if (bid < 2048) {
    int i = (bid * 256 + t) * 8;
    fl4 a = *(const fl4*)(x + i);
    fl4 b = *(const fl4*)(x + i + 4);
    u16x8 o;
    o[0] = f2bf_bits(a[0]); o[1] = f2bf_bits(a[1]); o[2] = f2bf_bits(a[2]); o[3] = f2bf_bits(a[3]);
    o[4] = f2bf_bits(b[0]); o[5] = f2bf_bits(b[1]); o[6] = f2bf_bits(b[2]); o[7] = f2bf_bits(b[3]);
    *(u16x8*)(xb + i) = o;
    return;
  }
  const int idx = bid - 2048;
  const int bx = idx & 63, by = idx >> 6;
  const float* src; unsigned short* dst; int NCOL, nt;
  if (bx < 48) { src = wqkv; dst = dqkv; NCOL = 3072; nt = bx * 64; }
  else         { src = wproj; dst = dproj; NCOL = 1024; nt = (bx - 48) * 64; }
  const float sc = (bx < 16) ? 0.18033688f : 1.0f;   // q-columns: fold scale*log2e into W
  const int kt = by * 64;
  {
    int r = t >> 2, c0 = (t & 3) * 16;
    const float* s = src + (size_t)(kt + r) * NCOL + nt + c0;
    #pragma unroll
    for (int j = 0; j < 4; ++j) {
      fl4 v = *(const fl4*)(s + j * 4);
      tile[r][c0 + j * 4 + 0] = v[0]; tile[r][c0 + j * 4 + 1] = v[1];
      tile[r][c0 + j * 4 + 2] = v[2]; tile[r][c0 + j * 4 + 3] = v[3];
    }
  }
  __syncthreads();
  {
    int n = t >> 2, kc = (t & 3) * 16;
    unsigned short* d = dst + (size_t)(nt + n) * 1024 + kt + kc;
    u16x8 o0, o1;
    #pragma unroll
    for (int j = 0; j < 8; ++j) o0[j] = f2bf_bits(tile[kc + j][n] * sc);
    #pragma unroll
    for (int j = 0; j < 8; ++j) o1[j] = f2bf_bits(tile[kc + 8 + j][n] * sc);
    *(u16x8*)d = o0;
    *(u16x8*)(d + 8) = o1;
  }
}

// ---------------- bf16 GEMM, 3-buffer mod-3 pipeline, counted vmcnt, 1 barrier/K-tile ----------
// C[M][Ncols] = A[M][1024] * Bt[Ncols][1024]^T, 128x128 tile, BK=32, 32 K-tiles.
// LDS 48KB = 3 bufs x (A 8KB + B 8KB). Tile j: vmcnt(4) [retire tile j's 4 loads; j+1's stay
// in flight] -> barrier -> stage tile j+2 into buf (j+2)%3 [last read by tile j-1, done
// before this barrier] -> compute from buf j%3. No vmcnt(0) drain in the loop.
// LDS layout: 128B rows hold 2 tile-rows; chunk slot kc stored at kc^((tr>>1)&3) -> 2-way
// bank aliasing only (free).
// MODE 0: QKV epilogue (q/k/v^T scatter; q pre-scaled via W); MODE 1: proj + bias, fp32
template <int MODE>
__global__ __launch_bounds__(256) void k_gemm(const unsigned short* __restrict__ A,
                                              const unsigned short* __restrict__ Bt,
                                              unsigned short* __restrict__ qp,
                                              unsigned short* __restrict__ kp,
                                              unsigned short* __restrict__ vtp,
                                              const float* __restrict__ bias,
                                              float* __restrict__ outp) {
  __shared__ __align__(16) char lds[49152];
  const int tid = threadIdx.x, lane = tid & 63, w = tid >> 6;
  const int wm = w >> 1, wn = w & 1;
  const int m0 = blockIdx.y * 128, n0 = blockIdx.x * 128;
  const char* Ab = (const char*)A + (size_t)m0 * 2048;
  const char* Bb = (const char*)Bt + (size_t)n0 * 2048;

  // staging: 4 chunks/thread (A: {tid, tid+256}, B: {tid, tid+256}); chunk c -> lr=c>>3,
  // s=c&7, p=s>>2, kc=(s&3)^(lr&3), tr=(lr<<1)|p; global off = tr*2048 + kc*16 (+ T*64)
  int goff[2];
  #pragma unroll
  for (int i = 0; i < 2; ++i) {
    int c = i * 256 + tid;
    int lr = c >> 3, s = c & 7, p = s >> 2, kc = (s & 3) ^ (lr & 3);
    goff[i] = (((lr << 1) | p) * 2048) + (kc << 4);
  }

  // frag read offsets: (tr, kc=lane>>4) -> (tr>>1)*128 + (tr&1)*64 + ((kc^((tr>>1)&3))<<4)
  int afo[4], bfo[4];
  #pragma unroll
  for (int mi = 0; mi < 4; ++mi) {
    int tr = wm * 64 + mi * 16 + (lane & 15), kc = lane >> 4;
    afo[mi] = (tr >> 1) * 128 + (tr & 1) * 64 + (((kc ^ ((tr >> 1) & 3))) << 4);
  }
  #pragma unroll
  for (int ni = 0; ni < 4; ++ni) {
    int tr = wn * 64 + ni * 16 + (lane & 15), kc = lane >> 4;
    bfo[ni] = (tr >> 1) * 128 + (tr & 1) * 64 + (((kc ^ ((tr >> 1) & 3))) << 4);
  }

  f32x4 acc[4][4];
  #pragma unroll
  for (int mi = 0; mi < 4; ++mi)
    #pragma unroll
    for (int ni = 0; ni < 4; ++ni) acc[mi][ni] = f32x4{0.f, 0.f, 0.f, 0.f};

#define GSTAGE(BUF, T)                                                         \
  do {                                                                         \
    char* dA = lds + (BUF) * 16384 + tid * 16;                                 \
    char* dB = dA + 8192;                                                      \
    gload_lds16(Ab + goff[0] + (T) * 64, dA);                                  \
    gload_lds16(Ab + goff[1] + (T) * 64, dA + 4096);                           \
    gload_lds16(Bb + goff[0] + (T) * 64, dB);                                  \
    gload_lds16(Bb + goff[1] + (T) * 64, dB + 4096);                           \
  } while (0)

#define GCOMP(BUF)                                                             \
  do {                                                                         \
    const char* LA = lds + (BUF) * 16384;                                      \
    const char* LB = LA + 8192;                                                \
    bf16x8 af[4], bfv[4];                                                      \
    _Pragma("unroll") for (int mi = 0; mi < 4; ++mi)                           \
      af[mi] = *(const bf16x8*)(LA + afo[mi]);                                 \
    _Pragma("unroll") for (int ni = 0; ni < 4; ++ni)                           \
      bfv[ni] = *(const bf16x8*)(LB + bfo[ni]);                                \
    _Pragma("unroll") for (int mi = 0; mi < 4; ++mi)                           \
      _Pragma("unroll") for (int ni = 0; ni < 4; ++ni)                         \
        acc[mi][ni] = MFMA16(af[mi], bfv[ni], acc[mi][ni]);                    \
  } while (0)

  GSTAGE(0, 0);
  GSTAGE(1, 1);
  {
    int bc = 0, bs = 2;
    for (int j = 0; j < 31; ++j) {
      asm volatile("s_waitcnt vmcnt(4)" ::: "memory");
      __builtin_amdgcn_s_barrier();
      if (j < 30) GSTAGE(bs, j + 2);
      GCOMP(bc);
      bc = (bc == 2) ? 0 : bc + 1;
      bs = (bs == 2) ? 0 : bs + 1;
    }
    asm volatile("s_waitcnt vmcnt(0)" ::: "memory");
    __builtin_amdgcn_s_barrier();
    GCOMP(1);  // tile 31 lives in buf 31%3 = 1
  }
#undef GCOMP
#undef GSTAGE

  if (MODE == 0) {
    #pragma unroll
    for (int mi = 0; mi < 4; ++mi) {
      int row0 = m0 + wm * 64 + mi * 16 + ((lane >> 4) << 2);
      int bb = row0 >> 10, nn0 = row0 & 1023;
      #pragma unroll
      for (int ni = 0; ni < 4; ++ni) {
        int col = n0 + wn * 64 + ni * 16 + (lane & 15);
        int tt = col >> 10, rem = col & 1023, h = rem >> 6, d = rem & 63;
        f32x4 a = acc[mi][ni];
        if (tt == 2) {
          u16x4 pv;
          pv[0] = f2bf_bits(a[0]); pv[1] = f2bf_bits(a[1]);
          pv[2] = f2bf_bits(a[2]); pv[3] = f2bf_bits(a[3]);
          *(u16x4*)(vtp + (((size_t)(bb * 16 + h) * 64 + d) << 10) + nn0) = pv;
        } else {
          unsigned short* dst = (tt == 0) ? qp : kp;
          size_t base = ((size_t)(bb * 16 + h)) << 16;
          #pragma unroll
          for (int r = 0; r < 4; ++r)
            dst[base + (size_t)(nn0 + r) * 64 + d] = f2bf_bits(a[r]);
        }
      }
    }
  } else {
    #pragma unroll
    for (int mi = 0; mi < 4; ++mi) {
      int row0 = m0 + wm * 64 + mi * 16 + ((lane >> 4) << 2);
      #pragma unroll
      for (int ni = 0; ni < 4; ++ni) {
        int col = n0 + wn * 64 + ni * 16 + (lane & 15);
        float bv = bias[col];
        f32x4 a = acc[mi][ni];
        #pragma unroll
        for (int r = 0; r < 4; ++r)
          outp[(size_t)(row0 + r) * 1024 + col] = a[r] + bv;
      }
    }
  }
}

// ---------------- flash attention: 8-wave blocks, 3-buffer counted-vmcnt pipeline ----------------
// r13 version unchanged: q pre-scaled (via W), full exp2-domain bias folded into the acc-INIT
// MFMA, raw v_exp_f32. 512 blocks = 64 heads x 8 q-chunks (128 rows).
__global__ __launch_bounds__(512, 4) void k_attn(const unsigned short* __restrict__ qp,
                                                 const unsigned short* __restrict__ kp,
                                                 const unsigned short* __restrict__ vtp,
                                                 const float* __restrict__ mask,
                                                 unsigned short* __restrict__ aop) {
  __shared__ __align__(16) char lds[49152];
  const int tid = threadIdx.x, lane = tid & 63, w = tid >> 6;
  const int hi = lane >> 5, lq = lane & 31;
  const int pair = w >> 2, qsub = w & 3;
  const int g = blockIdx.x;
  const int bh = (g & 7) * 8 + ((g >> 6) & 7);
  const int qc = (g >> 3) & 7;
  const int b = bh >> 4, h = bh & 15;
  const char* kb = (const char*)(kp + ((size_t)bh << 16));
  const char* vb = (const char*)(vtp + ((size_t)bh << 16));
  const unsigned short* qh = qp + ((size_t)bh << 16);
  const float* mrow = mask + b * 1024 + pair * 512;
  const int q0 = qc * 128 + qsub * 32;

  const int kpk = tid >> 8, krow = (tid >> 3) & 31, kslot = tid & 7;
  const char* gK = kb + (size_t)kpk * 65536 + (size_t)krow * 128
                   + ((kslot ^ (krow & 7)) * 16);                    // + t*4096
  const int vpk = tid >> 8, vrow = (tid >> 2) & 63, vslot = tid & 3;
  const char* gV = vb + (size_t)vpk * 1024 + (size_t)vrow * 2048
                   + ((vslot ^ ((vrow >> 1) & 3)) * 16);             // + t*64
  char* const dK = lds + tid * 16;          // + buf*16384
  char* const dV = lds + 8192 + tid * 16;   // + buf*16384

  int kfo[4], vfo[4];
  #pragma unroll
  for (int dc = 0; dc < 4; ++dc)
    kfo[dc] = lq * 128 + (((dc << 1) | hi) ^ (lq & 7)) * 16;
  #pragma unroll
  for (int ks = 0; ks < 2; ++ks)
    #pragma unroll
    for (int nb = 0; nb < 2; ++nb) {
      int row = nb * 32 + lq;
      vfo[ks * 2 + nb] = row * 64 + (((ks << 1) | hi) ^ ((row >> 1) & 3)) * 16;
    }

  int bws[16];
  #pragma unroll
  for (int t2 = 0; t2 < 16; ++t2) {
    float mv = mrow[t2 * 32 + lq];
    bws[t2] = (hi == 0) ? (int)f2bf_bits(fmaf(mv, 7.2134752f, -12.9842554f)) : 0;
  }

  bf16x8 qB[4];
  #pragma unroll
  for (int dc = 0; dc < 4; ++dc)
    qB[dc] = *(const bf16x8*)(qh + (q0 + lq) * 64 + dc * 16 + hi * 8);

  i32x4 onesw = {hi == 0 ? 0x3F80 : 0, 0, 0, 0};
  const bf16x8 onesB = __builtin_bit_cast(bf16x8, onesw);

  f32x16 Z16;
  #pragma unroll
  for (int i = 0; i < 16; ++i) Z16[i] = 0.f;

  f32x16 O0, O1;
  #pragma unroll
  for (int i = 0; i < 16; ++i) { O0[i] = 0.f; O1[i] = 0.f; }
  float lsum = 0.f;

#define STAGE(BUF, T)                                                          \
  do {                                                                         \
    gload_lds16(gK + (T) * 4096, dK + (BUF) * 16384);                          \
    gload_lds16(gV + (T) * 64,   dV + (BUF) * 16384);                          \
  } while (0)

#define VMCNT(N) asm volatile("s_waitcnt vmcnt(" #N ")" ::: "memory")

#define STEP(BUF, T, N)                                                        \
  do {                                                                         \
    VMCNT(N);                                                                  \
    __builtin_amdgcn_s_barrier();                                              \
    if ((T) + 2 <= 15) STAGE(((T) + 2) % 3, (T) + 2);                          \
    const char* K = lds + (BUF) * 16384 + pair * 4096;                         \
    const char* V = lds + (BUF) * 16384 + 8192 + pair * 4096;                  \
    f32x16 acc;                                                                \
    {                                                                          \
      i32x4 bwv = {bws[T], 0, 0, 0};                                           \
      acc = MFMA32(__builtin_bit_cast(bf16x8, bwv), onesB, Z16);               \
    }                                                                          \
    __builtin_amdgcn_s_setprio(1);                                             \
    _Pragma("unroll") for (int dc = 0; dc < 4; ++dc) {                         \
      bf16x8 kf = *(const bf16x8*)(K + kfo[dc]);                               \
      acc = MFMA32(kf, qB[dc], acc);                                           \
    }                                                                          \
    __builtin_amdgcn_s_setprio(0);                                             \
    float p[16];                                                               \
    _Pragma("unroll") for (int r = 0; r < 16; ++r) {                           \
      p[r] = EXP2R(acc[r]);                                                    \
      lsum += p[r];                                                            \
    }                                                                          \
    int X0 = cvtpk_bf16(p[0], p[1]),   X1 = cvtpk_bf16(p[2], p[3]);            \
    int Y0 = cvtpk_bf16(p[4], p[5]),   Y1 = cvtpk_bf16(p[6], p[7]);            \
    int Z0 = cvtpk_bf16(p[8], p[9]),   Z1 = cvtpk_bf16(p[10], p[11]);          \
    int W0 = cvtpk_bf16(p[12], p[13]), W1 = cvtpk_bf16(p[14], p[15]);          \
    plswap(X0, Y0); plswap(X1, Y1);                                            \
    plswap(Z0, W0); plswap(Z1, W1);                                            \
    i32x4 pa0v = {X0, X1, Y0, Y1};                                             \
    i32x4 pa1v = {Z0, Z1, W0, W1};                                             \
    const bf16x8 PA0 = __builtin_bit_cast(bf16x8, pa0v);                       \
    const bf16x8 PA1 = __builtin_bit_cast(bf16x8, pa1v);                       \
    bf16x8 va0 = *(const bf16x8*)(V + vfo[0]);                                 \
    bf16x8 va1 = *(const bf16x8*)(V + vfo[1]);                                 \
    bf16x8 vb0 = *(const bf16x8*)(V + vfo[2]);                                 \
    bf16x8 vb1 = *(const bf16x8*)(V + vfo[3]);                                 \
    __builtin_amdgcn_s_setprio(1);                                             \
    O0 = MFMA32(PA0, va0, O0);                                                 \
    O1 = MFMA32(PA0, va1, O1);                                                 \
    O0 = MFMA32(PA1, vb0, O0);                                                 \
    O1 = MFMA32(PA1, vb1, O1);                                                 \
    __builtin_amdgcn_s_setprio(0);                                             \
  } while (0)

  STAGE(0, 0);
  STAGE(1, 1);
  STEP(0, 0, 2);  STEP(1, 1, 2);  STEP(2, 2, 2);  STEP(0, 3, 2);
  STEP(1, 4, 2);  STEP(2, 5, 2);  STEP(0, 6, 2);  STEP(1, 7, 2);
  STEP(2, 8, 2);  STEP(0, 9, 2);  STEP(1, 10, 2); STEP(2, 11, 2);
  STEP(0, 12, 2); STEP(1, 13, 2); STEP(2, 14, 2); STEP(0, 15, 0);
#undef STEP
#undef VMCNT
#undef STAGE

  __syncthreads();
  float tot = lsum + __shfl_xor(lsum, 32);
  float* fx = (float*)lds;
  if (pair == 1) {
    int base = qsub * 64 * 34 + lane * 34;
    #pragma unroll
    for (int r = 0; r < 16; ++r) { fx[base + r] = O0[r]; fx[base + 16 + r] = O1[r]; }
    fx[base + 32] = tot;
  }
  __syncthreads();
  if (pair == 0) {
    int base = qsub * 64 * 34 + lane * 34;
    float invT = 1.0f / (tot + fx[base + 32]);
    #pragma unroll
    for (int r = 0; r < 16; ++r) {
      int qr = (r & 3) + 8 * (r >> 2) + 4 * hi;
      float iv = __shfl(invT, qr);
      float o0 = (O0[r] + fx[base + r]) * iv;
      float o1 = (O1[r] + fx[base + 16 + r]) * iv;
      size_t ob = (size_t)(b * 1024 + q0 + qr) * 1024 + h * 64 + lq;
      aop[ob] = f2bf_bits(o0);
      aop[ob + 32] = f2bf_bits(o1);
    }
  }
}

extern "C" void kernel_launch(void* const* d_in, const int* in_sizes, int n_in,
                              void* d_out, int out_size, void* d_ws, size_t ws_size,
                              hipStream_t stream) {
  const float* x     = (const float*)d_in[0];
  const float* mask  = (const float*)d_in[1];
  const float* wqkv  = (const float*)d_in[2];
  const float* wproj = (const float*)d_in[3];
  const float* bproj = (const float*)d_in[4];
  float* out = (float*)d_out;

  char* ws = (char*)d_ws;
  unsigned short* xb     = (unsigned short*)(ws);                 //  8 MB  x bf16 [4096][1024]
  unsigned short* wqkvt  = (unsigned short*)(ws + 8388608);       //  6 MB  W_qkv^T bf16 [3072][1024] (q cols pre-scaled)
  unsigned short* wprojt = (unsigned short*)(ws + 14680064);      //  2 MB  W_proj^T bf16 [1024][1024]
  unsigned short* qbuf   = (unsigned short*)(ws + 16777216);      //  8 MB  q [B,H,N,D] (pre-scaled)
  unsigned short* kbuf   = (unsigned short*)(ws + 25165824);      //  8 MB  k [B,H,N,D]
  unsigned short* vtbuf  = (unsigned short*)(ws + 33554432);      //  8 MB  v^T [B,H,D,N]
  unsigned short* aobuf  = (unsigned short*)(ws + 41943040);      //  8 MB  attn out bf16 [4096][1024]

  k_prep<<<dim3(3072), dim3(256), 0, stream>>>(x, xb, wqkv, wqkvt, wproj, wprojt);
  k_gemm<0><<<dim3(24, 32), dim3(256), 0, stream>>>(xb, wqkvt, qbuf, kbuf, vtbuf, nullptr, nullptr);
  k_attn<<<dim3(512), dim3(512), 0, stream>>>(qbuf, kbuf, vtbuf, mask, aobuf);
  k_gemm<1><<<dim3(8, 32), dim3(256), 0, stream>>>(aobuf, wprojt, nullptr, nullptr, nullptr, bproj, out);
}

// Round 15
// 89.828 us; speedup vs baseline: 1.2042x; 1.0171x over previous
//
#include <hip/hip_runtime.h>

typedef __attribute__((ext_vector_type(8))) short bf16x8;
typedef __attribute__((ext_vector_type(4))) float f32x4;
typedef __attribute__((ext_vector_type(16))) float f32x16;
typedef __attribute__((ext_vector_type(4))) float fl4;
typedef __attribute__((ext_vector_type(8))) unsigned short u16x8;
typedef __attribute__((ext_vector_type(4))) unsigned short u16x4;
typedef __attribute__((ext_vector_type(2))) int i32x2;
typedef __attribute__((ext_vector_type(4))) int i32x4;

#define MFMA16(A,B,C) __builtin_amdgcn_mfma_f32_16x16x32_bf16((A),(B),(C),0,0,0)
#define MFMA32(A,B,C) __builtin_amdgcn_mfma_f32_32x32x16_bf16((A),(B),(C),0,0,0)

#if __has_builtin(__builtin_amdgcn_exp2f)
#define EXP2R(x) __builtin_amdgcn_exp2f(x)
#else
#define EXP2R(x) exp2f(x)
#endif

__device__ __forceinline__ unsigned short f2bf_bits(float x) {
  union { float f; unsigned u; } v; v.f = x;
  unsigned r = v.u + 0x7fffu + ((v.u >> 16) & 1u);  // RTNE
  return (unsigned short)(r >> 16);
}

__device__ __forceinline__ void gload_lds16(const void* g, void* l) {
  __builtin_amdgcn_global_load_lds((const __attribute__((address_space(1))) void*)g,
                                   (__attribute__((address_space(3))) void*)l, 16, 0, 0);
}

// pack two f32 to packed bf16 (lo = a, hi = b), RTNE
__device__ __forceinline__ int cvtpk_bf16(float a, float b) {
  int r; asm("v_cvt_pk_bf16_f32 %0, %1, %2" : "=v"(r) : "v"(a), "v"(b)); return r;
}

// swap a's upper-lane-half with b's lower-lane-half (v_permlane32_swap_b32)
__device__ __forceinline__ void plswap(int& a, int& b) {
#if __has_builtin(__builtin_amdgcn_permlane32_swap)
  i32x2 r = __builtin_amdgcn_permlane32_swap(a, b, false, false);
  a = r[0]; b = r[1];
#else
  asm volatile("s_nop 1\n\tv_permlane32_swap_b32 %0, %1" : "+v"(a), "+v"(b));
#endif
}

// ---------------- fused prep: x fp32->bf16 (blocks 0-2047) + weight transpose-convert ----------------
__global__ __launch_bounds__(256) void k_prep(const float* __restrict__ x,
                                              unsigned short* __restrict__ xb,
                                              const float* __restrict__ wqkv,
                                              unsigned short* __restrict__ dqkv,
                                              const float* __restrict__ wproj,
                                              unsigned short* __restrict__ dproj) {
  __shared__ float tile[64][65];
  const int bid = blockIdx.x;
  const int t = threadIdx.x;
  if (bid < 2048) {
    int i = (bid * 256 + t) * 8;
    fl4 a = *(const fl4*)(x + i);
    fl4 b = *(const fl4*)(x + i + 4);
    u16x8 o;
    o[0] = f2bf_bits(a[0]); o[1] = f2bf_bits(a[1]); o[2] = f2bf_bits(a[2]); o[3] = f2bf_bits(a[3]);
    o[4] = f2bf_bits(b[0]); o[5] = f2bf_bits(b[1]); o[6] = f2bf_bits(b[2]); o[7] = f2bf_bits(b[3]);
    *(u16x8*)(xb + i) = o;
    return;
  }
  const int idx = bid - 2048;
  const int bx = idx & 63, by = idx >> 6;
  const float* src; unsigned short* dst; int NCOL, nt;
  if (bx < 48) { src = wqkv; dst = dqkv; NCOL = 3072; nt = bx * 64; }
  else         { src = wproj; dst = dproj; NCOL = 1024; nt = (bx - 48) * 64; }
  const float sc = (bx < 16) ? 0.18033688f : 1.0f;   // q-columns: fold scale*log2e into W
  const int kt = by * 64;
  {
    int r = t >> 2, c0 = (t & 3) * 16;
    const float* s = src + (size_t)(kt + r) * NCOL + nt + c0;
    #pragma unroll
    for (int j = 0; j < 4; ++j) {
      fl4 v = *(const fl4*)(s + j * 4);
      tile[r][c0 + j * 4 + 0] = v[0]; tile[r][c0 + j * 4 + 1] = v[1];
      tile[r][c0 + j * 4 + 2] = v[2]; tile[r][c0 + j * 4 + 3] = v[3];
    }
  }
  __syncthreads();
  {
    int n = t >> 2, kc = (t & 3) * 16;
    unsigned short* d = dst + (size_t)(nt + n) * 1024 + kt + kc;
    u16x8 o0, o1;
    #pragma unroll
    for (int j = 0; j < 8; ++j) o0[j] = f2bf_bits(tile[kc + j][n] * sc);
    #pragma unroll
    for (int j = 0; j < 8; ++j) o1[j] = f2bf_bits(tile[kc + 8 + j][n] * sc);
    *(u16x8*)d = o0;
    *(u16x8*)(d + 8) = o1;
  }
}

// ---------------- bf16 GEMM, 3-buffer mod-3 pipeline, 32x32x16 MFMA, XCD-swizzled grid ----------
// C[M][Ncols] = A[M][1024] * Bt[Ncols][1024]^T, 128x128 tile, BK=32, 32 K-tiles.
// Wave (wm,wn) computes 64x64 as 2x2 of 32x32; per K-tile 8 MFMA + 8 ds_read_b128.
// LDS 48KB = 3 bufs x (A 8KB + B 8KB); tile j: vmcnt(4) -> barrier -> stage j+2 -> compute j.
// LDS layout: 128B rows hold 2 tile-rows (64B each = 4 chunks); chunk kc at slot kc^(lr&3).
// 32x32 A/B frag: lane holds [row=lq][k = kh*16 + hi*8 ..+7] -> chunk 2*kh+hi; reads are
// 8-lane-broadcast conflict-free. C/D: col=lq, row=(reg&3)+8*(reg>>2)+4*hi (HW-verified).
// MODE 0: QKV epilogue (q/k/v^T scatter; q pre-scaled via W); MODE 1: proj + bias, fp32
template <int MODE>
__global__ __launch_bounds__(256) void k_gemm(const unsigned short* __restrict__ A,
                                              const unsigned short* __restrict__ Bt,
                                              unsigned short* __restrict__ qp,
                                              unsigned short* __restrict__ kp,
                                              unsigned short* __restrict__ vtp,
                                              const float* __restrict__ bias,
                                              float* __restrict__ outp) {
  __shared__ __align__(16) char lds[49152];
  const int tid = threadIdx.x, lane = tid & 63, w = tid >> 6;
  const int wm = w >> 1, wn = w & 1;
  const int lq = lane & 31, hi = lane >> 5;
  // XCD swizzle (bijective): gemm0 = 8x12 tile rectangle per XCD; gemm1 = 4x8.
  const int bid = blockIdx.x;
  const int xcd = bid & 7, s = bid >> 3;
  int ry, cx;
  if (MODE == 0) { ry = (xcd & 3) * 8 + s / 12; cx = (xcd >> 2) * 12 + s % 12; }
  else           { ry = xcd * 4 + s / 8;        cx = s % 8; }
  const int m0 = ry * 128, n0 = cx * 128;
  const char* Ab = (const char*)A + (size_t)m0 * 2048;
  const char* Bb = (const char*)Bt + (size_t)n0 * 2048;

  // staging: 4 chunks/thread; chunk c -> lr=c>>3, sl=c&7, p=sl>>2, kc=(sl&3)^(lr&3),
  // tr=(lr<<1)|p; global off = tr*2048 + kc*16 (+ T*64)
  int goff[2];
  #pragma unroll
  for (int i = 0; i < 2; ++i) {
    int c = i * 256 + tid;
    int lr = c >> 3, sl = c & 7, p = sl >> 2, kc = (sl & 3) ^ (lr & 3);
    goff[i] = (((lr << 1) | p) * 2048) + (kc << 4);
  }

  // 32x32 frag read offsets: tr = block row, chunk = 2*kh + hi
  int afo[2][2], bfo[2][2];
  #pragma unroll
  for (int rb = 0; rb < 2; ++rb)
    #pragma unroll
    for (int kh = 0; kh < 2; ++kh) {
      int tr = wm * 64 + rb * 32 + lq, ch = 2 * kh + hi;
      afo[rb][kh] = (tr >> 1) * 128 + (tr & 1) * 64 + ((ch ^ ((tr >> 1) & 3)) << 4);
      int tr2 = wn * 64 + rb * 32 + lq;
      bfo[rb][kh] = (tr2 >> 1) * 128 + (tr2 & 1) * 64 + ((ch ^ ((tr2 >> 1) & 3)) << 4);
    }

  f32x16 acc2[2][2];
  #pragma unroll
  for (int rb = 0; rb < 2; ++rb)
    #pragma unroll
    for (int cb = 0; cb < 2; ++cb)
      #pragma unroll
      for (int i = 0; i < 16; ++i) acc2[rb][cb][i] = 0.f;

#define GSTAGE(BUF, T)                                                         \
  do {                                                                         \
    char* dA = lds + (BUF) * 16384 + tid * 16;                                 \
    char* dB = dA + 8192;                                                      \
    gload_lds16(Ab + goff[0] + (T) * 64, dA);                                  \
    gload_lds16(Ab + goff[1] + (T) * 64, dA + 4096);                           \
    gload_lds16(Bb + goff[0] + (T) * 64, dB);                                  \
    gload_lds16(Bb + goff[1] + (T) * 64, dB + 4096);                           \
  } while (0)

#define GCOMP(BUF)                                                             \
  do {                                                                         \
    const char* LA = lds + (BUF) * 16384;                                      \
    const char* LB = LA + 8192;                                                \
    bf16x8 af[2][2], bfv[2][2];                                                \
    _Pragma("unroll") for (int rb = 0; rb < 2; ++rb)                           \
      _Pragma("unroll") for (int kh = 0; kh < 2; ++kh) {                       \
        af[rb][kh]  = *(const bf16x8*)(LA + afo[rb][kh]);                      \
        bfv[rb][kh] = *(const bf16x8*)(LB + bfo[rb][kh]);                      \
      }                                                                        \
    _Pragma("unroll") for (int rb = 0; rb < 2; ++rb)                           \
      _Pragma("unroll") for (int cb = 0; cb < 2; ++cb) {                       \
        acc2[rb][cb] = MFMA32(af[rb][0], bfv[cb][0], acc2[rb][cb]);            \
        acc2[rb][cb] = MFMA32(af[rb][1], bfv[cb][1], acc2[rb][cb]);            \
      }                                                                        \
  } while (0)

  GSTAGE(0, 0);
  GSTAGE(1, 1);
  {
    int bc = 0, bs = 2;
    for (int j = 0; j < 31; ++j) {
      asm volatile("s_waitcnt vmcnt(4)" ::: "memory");
      __builtin_amdgcn_s_barrier();
      if (j < 30) GSTAGE(bs, j + 2);
      GCOMP(bc);
      bc = (bc == 2) ? 0 : bc + 1;
      bs = (bs == 2) ? 0 : bs + 1;
    }
    asm volatile("s_waitcnt vmcnt(0)" ::: "memory");
    __builtin_amdgcn_s_barrier();
    GCOMP(1);  // tile 31 lives in buf 31%3 = 1
  }
#undef GCOMP
#undef GSTAGE

  #pragma unroll
  for (int rb = 0; rb < 2; ++rb)
    #pragma unroll
    for (int cb = 0; cb < 2; ++cb) {
      f32x16 a = acc2[rb][cb];
      int col = n0 + wn * 64 + cb * 32 + lq;
      if (MODE == 0) {
        int tt = col >> 10, rem = col & 1023, h = rem >> 6, d = rem & 63;
        #pragma unroll
        for (int g4 = 0; g4 < 4; ++g4) {
          int row0 = m0 + wm * 64 + rb * 32 + 8 * g4 + 4 * hi;
          int bb = row0 >> 10, nn0 = row0 & 1023;
          if (tt == 2) {
            u16x4 pv;
            pv[0] = f2bf_bits(a[4 * g4 + 0]); pv[1] = f2bf_bits(a[4 * g4 + 1]);
            pv[2] = f2bf_bits(a[4 * g4 + 2]); pv[3] = f2bf_bits(a[4 * g4 + 3]);
            *(u16x4*)(vtp + (((size_t)(bb * 16 + h) * 64 + d) << 10) + nn0) = pv;
          } else {
            unsigned short* dst = (tt == 0) ? qp : kp;
            size_t base = ((size_t)(bb * 16 + h)) << 16;
            #pragma unroll
            for (int s2 = 0; s2 < 4; ++s2)
              dst[base + (size_t)(nn0 + s2) * 64 + d] = f2bf_bits(a[4 * g4 + s2]);
          }
        }
      } else {
        float bv = bias[col];
        #pragma unroll
        for (int g4 = 0; g4 < 4; ++g4) {
          int row0 = m0 + wm * 64 + rb * 32 + 8 * g4 + 4 * hi;
          #pragma unroll
          for (int s2 = 0; s2 < 4; ++s2)
            outp[(size_t)(row0 + s2) * 1024 + col] = a[4 * g4 + s2] + bv;
        }
      }
    }
}

// ---------------- flash attention: 8-wave blocks, 3-buffer counted-vmcnt pipeline ----------------
// unchanged from r13/r14: q pre-scaled (via W), full exp2-domain bias folded into the acc-INIT
// MFMA, raw v_exp_f32. 512 blocks = 64 heads x 8 q-chunks (128 rows).
__global__ __launch_bounds__(512, 4) void k_attn(const unsigned short* __restrict__ qp,
                                                 const unsigned short* __restrict__ kp,
                                                 const unsigned short* __restrict__ vtp,
                                                 const float* __restrict__ mask,
                                                 unsigned short* __restrict__ aop) {
  __shared__ __align__(16) char lds[49152];
  const int tid = threadIdx.x, lane = tid & 63, w = tid >> 6;
  const int hi = lane >> 5, lq = lane & 31;
  const int pair = w >> 2, qsub = w & 3;
  const int g = blockIdx.x;
  const int bh = (g & 7) * 8 + ((g >> 6) & 7);
  const int qc = (g >> 3) & 7;
  const int b = bh >> 4, h = bh & 15;
  const char* kb = (const char*)(kp + ((size_t)bh << 16));
  const char* vb = (const char*)(vtp + ((size_t)bh << 16));
  const unsigned short* qh = qp + ((size_t)bh << 16);
  const float* mrow = mask + b * 1024 + pair * 512;
  const int q0 = qc * 128 + qsub * 32;

  const int kpk = tid >> 8, krow = (tid >> 3) & 31, kslot = tid & 7;
  const char* gK = kb + (size_t)kpk * 65536 + (size_t)krow * 128
                   + ((kslot ^ (krow & 7)) * 16);                    // + t*4096
  const int vpk = tid >> 8, vrow = (tid >> 2) & 63, vslot = tid & 3;
  const char* gV = vb + (size_t)vpk * 1024 + (size_t)vrow * 2048
                   + ((vslot ^ ((vrow >> 1) & 3)) * 16);             // + t*64
  char* const dK = lds + tid * 16;          // + buf*16384
  char* const dV = lds + 8192 + tid * 16;   // + buf*16384

  int kfo[4], vfo[4];
  #pragma unroll
  for (int dc = 0; dc < 4; ++dc)
    kfo[dc] = lq * 128 + (((dc << 1) | hi) ^ (lq & 7)) * 16;
  #pragma unroll
  for (int ks = 0; ks < 2; ++ks)
    #pragma unroll
    for (int nb = 0; nb < 2; ++nb) {
      int row = nb * 32 + lq;
      vfo[ks * 2 + nb] = row * 64 + (((ks << 1) | hi) ^ ((row >> 1) & 3)) * 16;
    }

  int bws[16];
  #pragma unroll
  for (int t2 = 0; t2 < 16; ++t2) {
    float mv = mrow[t2 * 32 + lq];
    bws[t2] = (hi == 0) ? (int)f2bf_bits(fmaf(mv, 7.2134752f, -12.9842554f)) : 0;
  }

  bf16x8 qB[4];
  #pragma unroll
  for (int dc = 0; dc < 4; ++dc)
    qB[dc] = *(const bf16x8*)(qh + (q0 + lq) * 64 + dc * 16 + hi * 8);

  i32x4 onesw = {hi == 0 ? 0x3F80 : 0, 0, 0, 0};
  const bf16x8 onesB = __builtin_bit_cast(bf16x8, onesw);

  f32x16 Z16;
  #pragma unroll
  for (int i = 0; i < 16; ++i) Z16[i] = 0.f;

  f32x16 O0, O1;
  #pragma unroll
  for (int i = 0; i < 16; ++i) { O0[i] = 0.f; O1[i] = 0.f; }
  float lsum = 0.f;

#define STAGE(BUF, T)                                                          \
  do {                                                                         \
    gload_lds16(gK + (T) * 4096, dK + (BUF) * 16384);                          \
    gload_lds16(gV + (T) * 64,   dV + (BUF) * 16384);                          \
  } while (0)

#define VMCNT(N) asm volatile("s_waitcnt vmcnt(" #N ")" ::: "memory")

#define STEP(BUF, T, N)                                                        \
  do {                                                                         \
    VMCNT(N);                                                                  \
    __builtin_amdgcn_s_barrier();                                              \
    if ((T) + 2 <= 15) STAGE(((T) + 2) % 3, (T) + 2);                          \
    const char* K = lds + (BUF) * 16384 + pair * 4096;                         \
    const char* V = lds + (BUF) * 16384 + 8192 + pair * 4096;                  \
    f32x16 acc;                                                                \
    {                                                                          \
      i32x4 bwv = {bws[T], 0, 0, 0};                                           \
      acc = MFMA32(__builtin_bit_cast(bf16x8, bwv), onesB, Z16);               \
    }                                                                          \
    __builtin_amdgcn_s_setprio(1);                                             \
    _Pragma("unroll") for (int dc = 0; dc < 4; ++dc) {                         \
      bf16x8 kf = *(const bf16x8*)(K + kfo[dc]);                               \
      acc = MFMA32(kf, qB[dc], acc);                                           \
    }                                                                          \
    __builtin_amdgcn_s_setprio(0);                                             \
    float p[16];                                                               \
    _Pragma("unroll") for (int r = 0; r < 16; ++r) {                           \
      p[r] = EXP2R(acc[r]);                                                    \
      lsum += p[r];                                                            \
    }                                                                          \
    int X0 = cvtpk_bf16(p[0], p[1]),   X1 = cvtpk_bf16(p[2], p[3]);            \
    int Y0 = cvtpk_bf16(p[4], p[5]),   Y1 = cvtpk_bf16(p[6], p[7]);            \
    int Z0 = cvtpk_bf16(p[8], p[9]),   Z1 = cvtpk_bf16(p[10], p[11]);          \
    int W0 = cvtpk_bf16(p[12], p[13]), W1 = cvtpk_bf16(p[14], p[15]);          \
    plswap(X0, Y0); plswap(X1, Y1);                                            \
    plswap(Z0, W0); plswap(Z1, W1);                                            \
    i32x4 pa0v = {X0, X1, Y0, Y1};                                             \
    i32x4 pa1v = {Z0, Z1, W0, W1};                                             \
    const bf16x8 PA0 = __builtin_bit_cast(bf16x8, pa0v);                       \
    const bf16x8 PA1 = __builtin_bit_cast(bf16x8, pa1v);                       \
    bf16x8 va0 = *(const bf16x8*)(V + vfo[0]);                                 \
    bf16x8 va1 = *(const bf16x8*)(V + vfo[1]);                                 \
    bf16x8 vb0 = *(const bf16x8*)(V + vfo[2]);                                 \
    bf16x8 vb1 = *(const bf16x8*)(V + vfo[3]);                                 \
    __builtin_amdgcn_s_setprio(1);                                             \
    O0 = MFMA32(PA0, va0, O0);                                                 \
    O1 = MFMA32(PA0, va1, O1);                                                 \
    O0 = MFMA32(PA1, vb0, O0);                                                 \
    O1 = MFMA32(PA1, vb1, O1);                                                 \
    __builtin_amdgcn_s_setprio(0);                                             \
  } while (0)

  STAGE(0, 0);
  STAGE(1, 1);
  STEP(0, 0, 2);  STEP(1, 1, 2);  STEP(2, 2, 2);  STEP(0, 3, 2);
  STEP(1, 4, 2);  STEP(2, 5, 2);  STEP(0, 6, 2);  STEP(1, 7, 2);
  STEP(2, 8, 2);  STEP(0, 9, 2);  STEP(1, 10, 2); STEP(2, 11, 2);
  STEP(0, 12, 2); STEP(1, 13, 2); STEP(2, 14, 2); STEP(0, 15, 0);
#undef STEP
#undef VMCNT
#undef STAGE

  __syncthreads();
  float tot = lsum + __shfl_xor(lsum, 32);
  float* fx = (float*)lds;
  if (pair == 1) {
    int base = qsub * 64 * 34 + lane * 34;
    #pragma unroll
    for (int r = 0; r < 16; ++r) { fx[base + r] = O0[r]; fx[base + 16 + r] = O1[r]; }
    fx[base + 32] = tot;
  }
  __syncthreads();
  if (pair == 0) {
    int base = qsub * 64 * 34 + lane * 34;
    float invT = 1.0f / (tot + fx[base + 32]);
    #pragma unroll
    for (int r = 0; r < 16; ++r) {
      int qr = (r & 3) + 8 * (r >> 2) + 4 * hi;
      float iv = __shfl(invT, qr);
      float o0 = (O0[r] + fx[base + r]) * iv;
      float o1 = (O1[r] + fx[base + 16 + r]) * iv;
      size_t ob = (size_t)(b * 1024 + q0 + qr) * 1024 + h * 64 + lq;
      aop[ob] = f2bf_bits(o0);
      aop[ob + 32] = f2bf_bits(o1);
    }
  }
}

extern "C" void kernel_launch(void* const* d_in, const int* in_sizes, int n_in,
                              void* d_out, int out_size, void* d_ws, size_t ws_size,
                              hipStream_t stream) {
  const float* x     = (const float*)d_in[0];
  const float* mask  = (const float*)d_in[1];
  const float* wqkv  = (const float*)d_in[2];
  const float* wproj = (const float*)d_in[3];
  const float* bproj = (const float*)d_in[4];
  float* out = (float*)d_out;

  char* ws = (char*)d_ws;
  unsigned short* xb     = (unsigned short*)(ws);                 //  8 MB  x bf16 [4096][1024]
  unsigned short* wqkvt  = (unsigned short*)(ws + 8388608);       //  6 MB  W_qkv^T bf16 [3072][1024] (q cols pre-scaled)
  unsigned short* wprojt = (unsigned short*)(ws + 14680064);      //  2 MB  W_proj^T bf16 [1024][1024]
  unsigned short* qbuf   = (unsigned short*)(ws + 16777216);      //  8 MB  q [B,H,N,D] (pre-scaled)
  unsigned short* kbuf   = (unsigned short*)(ws + 25165824);      //  8 MB  k [B,H,N,D]
  unsigned short* vtbuf  = (unsigned short*)(ws + 33554432);      //  8 MB  v^T [B,H,D,N]
  unsigned short* aobuf  = (unsigned short*)(ws + 41943040);      //  8 MB  attn out bf16 [4096][1024]

  k_prep<<<dim3(3072), dim3(256), 0, stream>>>(x, xb, wqkv, wqkvt, wproj, wprojt);
  k_gemm<0><<<dim3(768), dim3(256), 0, stream>>>(xb, wqkvt, qbuf, kbuf, vtbuf, nullptr, nullptr);
  k_attn<<<dim3(512), dim3(512), 0, stream>>>(qbuf, kbuf, vtbuf, mask, aobuf);
  k_gemm<1><<<dim3(256), dim3(256), 0, stream>>>(aobuf, wprojt, nullptr, nullptr, nullptr, bproj, out);
}

// Round 16
// 89.435 us; speedup vs baseline: 1.2095x; 1.0044x over previous
//
#include <hip/hip_runtime.h>

typedef __attribute__((ext_vector_type(8))) short bf16x8;
typedef __attribute__((ext_vector_type(4))) float f32x4;
typedef __attribute__((ext_vector_type(16))) float f32x16;
typedef __attribute__((ext_vector_type(4))) float fl4;
typedef __attribute__((ext_vector_type(8))) unsigned short u16x8;
typedef __attribute__((ext_vector_type(4))) unsigned short u16x4;
typedef __attribute__((ext_vector_type(2))) int i32x2;
typedef __attribute__((ext_vector_type(4))) int i32x4;

#define MFMA16(A,B,C) __builtin_amdgcn_mfma_f32_16x16x32_bf16((A),(B),(C),0,0,0)
#define MFMA32(A,B,C) __builtin_amdgcn_mfma_f32_32x32x16_bf16((A),(B),(C),0,0,0)

#if __has_builtin(__builtin_amdgcn_exp2f)
#define EXP2R(x) __builtin_amdgcn_exp2f(x)
#else
#define EXP2R(x) exp2f(x)
#endif

__device__ __forceinline__ unsigned short f2bf_bits(float x) {
  union { float f; unsigned u; } v; v.f = x;
  unsigned r = v.u + 0x7fffu + ((v.u >> 16) & 1u);  // RTNE
  return (unsigned short)(r >> 16);
}

__device__ __forceinline__ void gload_lds16(const void* g, void* l) {
  __builtin_amdgcn_global_load_lds((const __attribute__((address_space(1))) void*)g,
                                   (__attribute__((address_space(3))) void*)l, 16, 0, 0);
}

// pack two f32 to packed bf16 (lo = a, hi = b), RTNE
__device__ __forceinline__ int cvtpk_bf16(float a, float b) {
  int r; asm("v_cvt_pk_bf16_f32 %0, %1, %2" : "=v"(r) : "v"(a), "v"(b)); return r;
}

// swap a's upper-lane-half with b's lower-lane-half (v_permlane32_swap_b32)
__device__ __forceinline__ void plswap(int& a, int& b) {
#if __has_builtin(__builtin_amdgcn_permlane32_swap)
  i32x2 r = __builtin_amdgcn_permlane32_swap(a, b, false, false);
  a = r[0]; b = r[1];
#else
  asm volatile("s_nop 1\n\tv_permlane32_swap_b32 %0, %1" : "+v"(a), "+v"(b));
#endif
}

// ---------------- fused prep: x fp32->bf16 (blocks 0-2047) + weight transpose-convert ----------------
__global__ __launch_bounds__(256) void k_prep(const float* __restrict__ x,
                                              unsigned short* __restrict__ xb,
                                              const float* __restrict__ wqkv,
                                              unsigned short* __restrict__ dqkv,
                                              const float* __restrict__ wproj,
                                              unsigned short* __restrict__ dproj) {
  __shared__ float tile[64][65];
  const int bid = blockIdx.x;
  const int t = threadIdx.x;
  if (bid < 2048) {
    int i = (bid * 256 + t) * 8;
    fl4 a = *(const fl4*)(x + i);
    fl4 b = *(const fl4*)(x + i + 4);
    u16x8 o;
    o[0] = f2bf_bits(a[0]); o[1] = f2bf_bits(a[1]); o[2] = f2bf_bits(a[2]); o[3] = f2bf_bits(a[3]);
    o[4] = f2bf_bits(b[0]); o[5] = f2bf_bits(b[1]); o[6] = f2bf_bits(b[2]); o[7] = f2bf_bits(b[3]);
    *(u16x8*)(xb + i) = o;
    return;
  }
  const int idx = bid - 2048;
  const int bx = idx & 63, by = idx >> 6;
  const float* src; unsigned short* dst; int NCOL, nt;
  if (bx < 48) { src = wqkv; dst = dqkv; NCOL = 3072; nt = bx * 64; }
  else         { src = wproj; dst = dproj; NCOL = 1024; nt = (bx - 48) * 64; }
  const float sc = (bx < 16) ? 0.18033688f : 1.0f;   // q-columns: fold scale*log2e into W
  const int kt = by * 64;
  {
    int r = t >> 2, c0 = (t & 3) * 16;
    const float* s = src + (size_t)(kt + r) * NCOL + nt + c0;
    #pragma unroll
    for (int j = 0; j < 4; ++j) {
      fl4 v = *(const fl4*)(s + j * 4);
      tile[r][c0 + j * 4 + 0] = v[0]; tile[r][c0 + j * 4 + 1] = v[1];
      tile[r][c0 + j * 4 + 2] = v[2]; tile[r][c0 + j * 4 + 3] = v[3];
    }
  }
  __syncthreads();
  {
    int n = t >> 2, kc = (t & 3) * 16;
    unsigned short* d = dst + (size_t)(nt + n) * 1024 + kt + kc;
    u16x8 o0, o1;
    #pragma unroll
    for (int j = 0; j < 8; ++j) o0[j] = f2bf_bits(tile[kc + j][n] * sc);
    #pragma unroll
    for (int j = 0; j < 8; ++j) o1[j] = f2bf_bits(tile[kc + 8 + j][n] * sc);
    *(u16x8*)d = o0;
    *(u16x8*)(d + 8) = o1;
  }
}

// ---------------- bf16 GEMM, 3-buffer mod-3 pipeline, 16x16x32 MFMA, XCD-swizzled grid ----------
// C[M][Ncols] = A[M][1024] * Bt[Ncols][1024]^T, 128x128 tile, BK=32, 32 K-tiles.
// r14's frag/LDS pattern (measured 0 bank conflicts) + r15's bijective XCD swizzle
// (measured FETCH 37->27 MB). LDS 48KB = 3 bufs x (A 8KB + B 8KB); tile j: vmcnt(4) ->
// barrier -> stage j+2 -> compute j. LDS layout: 128B rows hold 2 tile-rows; chunk kc at
// slot kc^(tr>>1 & 3).
// MODE 0: QKV epilogue (q/k/v^T scatter; q pre-scaled via W); MODE 1: proj + bias, fp32
template <int MODE>
__global__ __launch_bounds__(256) void k_gemm(const unsigned short* __restrict__ A,
                                              const unsigned short* __restrict__ Bt,
                                              unsigned short* __restrict__ qp,
                                              unsigned short* __restrict__ kp,
                                              unsigned short* __restrict__ vtp,
                                              const float* __restrict__ bias,
                                              float* __restrict__ outp) {
  __shared__ __align__(16) char lds[49152];
  const int tid = threadIdx.x, lane = tid & 63, w = tid >> 6;
  const int wm = w >> 1, wn = w & 1;
  // XCD swizzle (bijective): gemm0 = 8x12 tile rectangle per XCD; gemm1 = 4x8.
  const int bid = blockIdx.x;
  const int xcd = bid & 7, s = bid >> 3;
  int ry, cx;
  if (MODE == 0) { ry = (xcd & 3) * 8 + s / 12; cx = (xcd >> 2) * 12 + s % 12; }
  else           { ry = xcd * 4 + s / 8;        cx = s % 8; }
  const int m0 = ry * 128, n0 = cx * 128;
  const char* Ab = (const char*)A + (size_t)m0 * 2048;
  const char* Bb = (const char*)Bt + (size_t)n0 * 2048;

  // staging: 4 chunks/thread (A: {tid, tid+256}, B: {tid, tid+256}); chunk c -> lr=c>>3,
  // sl=c&7, p=sl>>2, kc=(sl&3)^(lr&3), tr=(lr<<1)|p; global off = tr*2048 + kc*16 (+ T*64)
  int goff[2];
  #pragma unroll
  for (int i = 0; i < 2; ++i) {
    int c = i * 256 + tid;
    int lr = c >> 3, sl = c & 7, p = sl >> 2, kc = (sl & 3) ^ (lr & 3);
    goff[i] = (((lr << 1) | p) * 2048) + (kc << 4);
  }

  // frag read offsets: (tr, kc=lane>>4) -> (tr>>1)*128 + (tr&1)*64 + ((kc^((tr>>1)&3))<<4)
  int afo[4], bfo[4];
  #pragma unroll
  for (int mi = 0; mi < 4; ++mi) {
    int tr = wm * 64 + mi * 16 + (lane & 15), kc = lane >> 4;
    afo[mi] = (tr >> 1) * 128 + (tr & 1) * 64 + (((kc ^ ((tr >> 1) & 3))) << 4);
  }
  #pragma unroll
  for (int ni = 0; ni < 4; ++ni) {
    int tr = wn * 64 + ni * 16 + (lane & 15), kc = lane >> 4;
    bfo[ni] = (tr >> 1) * 128 + (tr & 1) * 64 + (((kc ^ ((tr >> 1) & 3))) << 4);
  }

  f32x4 acc[4][4];
  #pragma unroll
  for (int mi = 0; mi < 4; ++mi)
    #pragma unroll
    for (int ni = 0; ni < 4; ++ni) acc[mi][ni] = f32x4{0.f, 0.f, 0.f, 0.f};

#define GSTAGE(BUF, T)                                                         \
  do {                                                                         \
    char* dA = lds + (BUF) * 16384 + tid * 16;                                 \
    char* dB = dA + 8192;                                                      \
    gload_lds16(Ab + goff[0] + (T) * 64, dA);                                  \
    gload_lds16(Ab + goff[1] + (T) * 64, dA + 4096);                           \
    gload_lds16(Bb + goff[0] + (T) * 64, dB);                                  \
    gload_lds16(Bb + goff[1] + (T) * 64, dB + 4096);                           \
  } while (0)

#define GCOMP(BUF)                                                             \
  do {                                                                         \
    const char* LA = lds + (BUF) * 16384;                                      \
    const char* LB = LA + 8192;                                                \
    bf16x8 af[4], bfv[4];                                                      \
    _Pragma("unroll") for (int mi = 0; mi < 4; ++mi)                           \
      af[mi] = *(const bf16x8*)(LA + afo[mi]);                                 \
    _Pragma("unroll") for (int ni = 0; ni < 4; ++ni)                           \
      bfv[ni] = *(const bf16x8*)(LB + bfo[ni]);                                \
    _Pragma("unroll") for (int mi = 0; mi < 4; ++mi)                           \
      _Pragma("unroll") for (int ni = 0; ni < 4; ++ni)                         \
        acc[mi][ni] = MFMA16(af[mi], bfv[ni], acc[mi][ni]);                    \
  } while (0)

  GSTAGE(0, 0);
  GSTAGE(1, 1);
  {
    int bc = 0, bs = 2;
    for (int j = 0; j < 31; ++j) {
      asm volatile("s_waitcnt vmcnt(4)" ::: "memory");
      __builtin_amdgcn_s_barrier();
      if (j < 30) GSTAGE(bs, j + 2);
      GCOMP(bc);
      bc = (bc == 2) ? 0 : bc + 1;
      bs = (bs == 2) ? 0 : bs + 1;
    }
    asm volatile("s_waitcnt vmcnt(0)" ::: "memory");
    __builtin_amdgcn_s_barrier();
    GCOMP(1);  // tile 31 lives in buf 31%3 = 1
  }
#undef GCOMP
#undef GSTAGE

  if (MODE == 0) {
    #pragma unroll
    for (int mi = 0; mi < 4; ++mi) {
      int row0 = m0 + wm * 64 + mi * 16 + ((lane >> 4) << 2);
      int bb = row0 >> 10, nn0 = row0 & 1023;
      #pragma unroll
      for (int ni = 0; ni < 4; ++ni) {
        int col = n0 + wn * 64 + ni * 16 + (lane & 15);
        int tt = col >> 10, rem = col & 1023, h = rem >> 6, d = rem & 63;
        f32x4 a = acc[mi][ni];
        if (tt == 2) {
          u16x4 pv;
          pv[0] = f2bf_bits(a[0]); pv[1] = f2bf_bits(a[1]);
          pv[2] = f2bf_bits(a[2]); pv[3] = f2bf_bits(a[3]);
          *(u16x4*)(vtp + (((size_t)(bb * 16 + h) * 64 + d) << 10) + nn0) = pv;
        } else {
          unsigned short* dst = (tt == 0) ? qp : kp;
          size_t base = ((size_t)(bb * 16 + h)) << 16;
          #pragma unroll
          for (int r = 0; r < 4; ++r)
            dst[base + (size_t)(nn0 + r) * 64 + d] = f2bf_bits(a[r]);
        }
      }
    }
  } else {
    #pragma unroll
    for (int mi = 0; mi < 4; ++mi) {
      int row0 = m0 + wm * 64 + mi * 16 + ((lane >> 4) << 2);
      #pragma unroll
      for (int ni = 0; ni < 4; ++ni) {
        int col = n0 + wn * 64 + ni * 16 + (lane & 15);
        float bv = bias[col];
        f32x4 a = acc[mi][ni];
        #pragma unroll
        for (int r = 0; r < 4; ++r)
          outp[(size_t)(row0 + r) * 1024 + col] = a[r] + bv;
      }
    }
  }
}

// ---------------- flash attention: 8-wave blocks, 3-buffer counted-vmcnt pipeline ----------------
// unchanged: q pre-scaled (via W), full exp2-domain bias folded into the acc-INIT MFMA,
// raw v_exp_f32. 512 blocks = 64 heads x 8 q-chunks (128 rows).
__global__ __launch_bounds__(512, 4) void k_attn(const unsigned short* __restrict__ qp,
                                                 const unsigned short* __restrict__ kp,
                                                 const unsigned short* __restrict__ vtp,
                                                 const float* __restrict__ mask,
                                                 unsigned short* __restrict__ aop) {
  __shared__ __align__(16) char lds[49152];
  const int tid = threadIdx.x, lane = tid & 63, w = tid >> 6;
  const int hi = lane >> 5, lq = lane & 31;
  const int pair = w >> 2, qsub = w & 3;
  const int g = blockIdx.x;
  const int bh = (g & 7) * 8 + ((g >> 6) & 7);
  const int qc = (g >> 3) & 7;
  const int b = bh >> 4, h = bh & 15;
  const char* kb = (const char*)(kp + ((size_t)bh << 16));
  const char* vb = (const char*)(vtp + ((size_t)bh << 16));
  const unsigned short* qh = qp + ((size_t)bh << 16);
  const float* mrow = mask + b * 1024 + pair * 512;
  const int q0 = qc * 128 + qsub * 32;

  const int kpk = tid >> 8, krow = (tid >> 3) & 31, kslot = tid & 7;
  const char* gK = kb + (size_t)kpk * 65536 + (size_t)krow * 128
                   + ((kslot ^ (krow & 7)) * 16);                    // + t*4096
  const int vpk = tid >> 8, vrow = (tid >> 2) & 63, vslot = tid & 3;
  const char* gV = vb + (size_t)vpk * 1024 + (size_t)vrow * 2048
                   + ((vslot ^ ((vrow >> 1) & 3)) * 16);             // + t*64
  char* const dK = lds + tid * 16;          // + buf*16384
  char* const dV = lds + 8192 + tid * 16;   // + buf*16384

  int kfo[4], vfo[4];
  #pragma unroll
  for (int dc = 0; dc < 4; ++dc)
    kfo[dc] = lq * 128 + (((dc << 1) | hi) ^ (lq & 7)) * 16;
  #pragma unroll
  for (int ks = 0; ks < 2; ++ks)
    #pragma unroll
    for (int nb = 0; nb < 2; ++nb) {
      int row = nb * 32 + lq;
      vfo[ks * 2 + nb] = row * 64 + (((ks << 1) | hi) ^ ((row >> 1) & 3)) * 16;
    }

  int bws[16];
  #pragma unroll
  for (int t2 = 0; t2 < 16; ++t2) {
    float mv = mrow[t2 * 32 + lq];
    bws[t2] = (hi == 0) ? (int)f2bf_bits(fmaf(mv, 7.2134752f, -12.9842554f)) : 0;
  }

  bf16x8 qB[4];
  #pragma unroll
  for (int dc = 0; dc < 4; ++dc)
    qB[dc] = *(const bf16x8*)(qh + (q0 + lq) * 64 + dc * 16 + hi * 8);

  i32x4 onesw = {hi == 0 ? 0x3F80 : 0, 0, 0, 0};
  const bf16x8 onesB = __builtin_bit_cast(bf16x8, onesw);

  f32x16 Z16;
  #pragma unroll
  for (int i = 0; i < 16; ++i) Z16[i] = 0.f;

  f32x16 O0, O1;
  #pragma unroll
  for (int i = 0; i < 16; ++i) { O0[i] = 0.f; O1[i] = 0.f; }
  float lsum = 0.f;

#define STAGE(BUF, T)                                                          \
  do {                                                                         \
    gload_lds16(gK + (T) * 4096, dK + (BUF) * 16384);                          \
    gload_lds16(gV + (T) * 64,   dV + (BUF) * 16384);                          \
  } while (0)

#define VMCNT(N) asm volatile("s_waitcnt vmcnt(" #N ")" ::: "memory")

#define STEP(BUF, T, N)                                                        \
  do {                                                                         \
    VMCNT(N);                                                                  \
    __builtin_amdgcn_s_barrier();                                              \
    if ((T) + 2 <= 15) STAGE(((T) + 2) % 3, (T) + 2);                          \
    const char* K = lds + (BUF) * 16384 + pair * 4096;                         \
    const char* V = lds + (BUF) * 16384 + 8192 + pair * 4096;                  \
    f32x16 acc;                                                                \
    {                                                                          \
      i32x4 bwv = {bws[T], 0, 0, 0};                                           \
      acc = MFMA32(__builtin_bit_cast(bf16x8, bwv), onesB, Z16);               \
    }                                                                          \
    __builtin_amdgcn_s_setprio(1);                                             \
    _Pragma("unroll") for (int dc = 0; dc < 4; ++dc) {                         \
      bf16x8 kf = *(const bf16x8*)(K + kfo[dc]);                               \
      acc = MFMA32(kf, qB[dc], acc);                                           \
    }                                                                          \
    __builtin_amdgcn_s_setprio(0);                                             \
    float p[16];                                                               \
    _Pragma("unroll") for (int r = 0; r < 16; ++r) {                           \
      p[r] = EXP2R(acc[r]);                                                    \
      lsum += p[r];                                                            \
    }                                                                          \
    int X0 = cvtpk_bf16(p[0], p[1]),   X1 = cvtpk_bf16(p[2], p[3]);            \
    int Y0 = cvtpk_bf16(p[4], p[5]),   Y1 = cvtpk_bf16(p[6], p[7]);            \
    int Z0 = cvtpk_bf16(p[8], p[9]),   Z1 = cvtpk_bf16(p[10], p[11]);          \
    int W0 = cvtpk_bf16(p[12], p[13]), W1 = cvtpk_bf16(p[14], p[15]);          \
    plswap(X0, Y0); plswap(X1, Y1);                                            \
    plswap(Z0, W0); plswap(Z1, W1);                                            \
    i32x4 pa0v = {X0, X1, Y0, Y1};                                             \
    i32x4 pa1v = {Z0, Z1, W0, W1};                                             \
    const bf16x8 PA0 = __builtin_bit_cast(bf16x8, pa0v);                       \
    const bf16x8 PA1 = __builtin_bit_cast(bf16x8, pa1v);                       \
    bf16x8 va0 = *(const bf16x8*)(V + vfo[0]);                                 \
    bf16x8 va1 = *(const bf16x8*)(V + vfo[1]);                                 \
    bf16x8 vb0 = *(const bf16x8*)(V + vfo[2]);                                 \
    bf16x8 vb1 = *(const bf16x8*)(V + vfo[3]);                                 \
    __builtin_amdgcn_s_setprio(1);                                             \
    O0 = MFMA32(PA0, va0, O0);                                                 \
    O1 = MFMA32(PA0, va1, O1);                                                 \
    O0 = MFMA32(PA1, vb0, O0);                                                 \
    O1 = MFMA32(PA1, vb1, O1);                                                 \
    __builtin_amdgcn_s_setprio(0);                                             \
  } while (0)

  STAGE(0, 0);
  STAGE(1, 1);
  STEP(0, 0, 2);  STEP(1, 1, 2);  STEP(2, 2, 2);  STEP(0, 3, 2);
  STEP(1, 4, 2);  STEP(2, 5, 2);  STEP(0, 6, 2);  STEP(1, 7, 2);
  STEP(2, 8, 2);  STEP(0, 9, 2);  STEP(1, 10, 2); STEP(2, 11, 2);
  STEP(0, 12, 2); STEP(1, 13, 2); STEP(2, 14, 2); STEP(0, 15, 0);
#undef STEP
#undef VMCNT
#undef STAGE

  __syncthreads();
  float tot = lsum + __shfl_xor(lsum, 32);
  float* fx = (float*)lds;
  if (pair == 1) {
    int base = qsub * 64 * 34 + lane * 34;
    #pragma unroll
    for (int r = 0; r < 16; ++r) { fx[base + r] = O0[r]; fx[base + 16 + r] = O1[r]; }
    fx[base + 32] = tot;
  }
  __syncthreads();
  if (pair == 0) {
    int base = qsub * 64 * 34 + lane * 34;
    float invT = 1.0f / (tot + fx[base + 32]);
    #pragma unroll
    for (int r = 0; r < 16; ++r) {
      int qr = (r & 3) + 8 * (r >> 2) + 4 * hi;
      float iv = __shfl(invT, qr);
      float o0 = (O0[r] + fx[base + r]) * iv;
      float o1 = (O1[r] + fx[base + 16 + r]) * iv;
      size_t ob = (size_t)(b * 1024 + q0 + qr) * 1024 + h * 64 + lq;
      aop[ob] = f2bf_bits(o0);
      aop[ob + 32] = f2bf_bits(o1);
    }
  }
}

extern "C" void kernel_launch(void* const* d_in, const int* in_sizes, int n_in,
                              void* d_out, int out_size, void* d_ws, size_t ws_size,
                              hipStream_t stream) {
  const float* x     = (const float*)d_in[0];
  const float* mask  = (const float*)d_in[1];
  const float* wqkv  = (const float*)d_in[2];
  const float* wproj = (const float*)d_in[3];
  const float* bproj = (const float*)d_in[4];
  float* out = (float*)d_out;

  char* ws = (char*)d_ws;
  unsigned short* xb     = (unsigned short*)(ws);                 //  8 MB  x bf16 [4096][1024]
  unsigned short* wqkvt  = (unsigned short*)(ws + 8388608);       //  6 MB  W_qkv^T bf16 [3072][1024] (q cols pre-scaled)
  unsigned short* wprojt = (unsigned short*)(ws + 14680064);      //  2 MB  W_proj^T bf16 [1024][1024]
  unsigned short* qbuf   = (unsigned short*)(ws + 16777216);      //  8 MB  q [B,H,N,D] (pre-scaled)
  unsigned short* kbuf   = (unsigned short*)(ws + 25165824);      //  8 MB  k [B,H,N,D]
  unsigned short* vtbuf  = (unsigned short*)(ws + 33554432);      //  8 MB  v^T [B,H,D,N]
  unsigned short* aobuf  = (unsigned short*)(ws + 41943040);      //  8 MB  attn out bf16 [4096][1024]

  k_prep<<<dim3(3072), dim3(256), 0, stream>>>(x, xb, wqkv, wqkvt, wproj, wprojt);
  k_gemm<0><<<dim3(768), dim3(256), 0, stream>>>(xb, wqkvt, qbuf, kbuf, vtbuf, nullptr, nullptr);
  k_attn<<<dim3(512), dim3(512), 0, stream>>>(qbuf, kbuf, vtbuf, mask, aobuf);
  k_gemm<1><<<dim3(256), dim3(256), 0, stream>>>(aobuf, wprojt, nullptr, nullptr, nullptr, bproj, out);
}